// Round 12
// baseline (154.143 us; speedup 1.0000x reference)
//
#include <hip/hip_runtime.h>
#include <stdint.h>

// Problem constants (fixed-shape problem)
#define SEQ    2048
#define DMODEL 2048
#define NHEAD  32
#define NKV    8
#define HDIM   64
#define NQKV   3072   // 2048 q + 512 k + 512 v

typedef __bf16 bf16x8 __attribute__((ext_vector_type(8)));
typedef float  f32x4  __attribute__((ext_vector_type(4)));

#define SCALE2 0.180336880f   // 0.125 * log2(e): scores land in log2 domain
#define THR2   12.0f          // defer-max threshold (log2 domain); P <= 2^12

__device__ __forceinline__ ushort bf(float f){
  __bf16 h = (__bf16)f;               // native RNE convert on gfx950
  return __builtin_bit_cast(unsigned short, h);
}
__device__ __forceinline__ float b2f(ushort v){
  union { uint32_t u; float f; } a; a.u = ((uint32_t)v) << 16; return a.f;
}

__device__ __forceinline__ void gl_lds16(const void* g, void* l){
  __builtin_amdgcn_global_load_lds(
      (const __attribute__((address_space(1))) uint32_t*)g,
      (__attribute__((address_space(3))) uint32_t*)l, 16, 0, 0);
}

// ------------- all f32->bf16 converts in one kernel -------------
__global__ __launch_bounds__(256) void k_cvt_all(const float* __restrict__ x,
                                                 const float* __restrict__ wq,
                                                 const float* __restrict__ wk,
                                                 const float* __restrict__ wv,
                                                 const float* __restrict__ wo,
                                                 ushort* __restrict__ xb,
                                                 ushort* __restrict__ wcat,
                                                 ushort* __restrict__ wob){
  int i = blockIdx.x * 256 + threadIdx.x;
  const float* src; ushort* dst; int s4; int d4;
  if (i < 1048576)      { src = x;  dst = xb;   s4 = i;           d4 = s4; }
  else if (i < 2097152) { src = wq; dst = wcat; s4 = i - 1048576; d4 = s4; }
  else if (i < 2359296) { src = wk; dst = wcat; s4 = i - 2097152; d4 = s4 + 1048576; }
  else if (i < 2621440) { src = wv; dst = wcat; s4 = i - 2359296; d4 = s4 + 1310720; }
  else                  { src = wo; dst = wob;  s4 = i - 2621440; d4 = s4; }
  float4 v = reinterpret_cast<const float4*>(src)[s4];
  ushort4 o;
  o.x = bf(v.x); o.y = bf(v.y); o.z = bf(v.z); o.w = bf(v.w);
  reinterpret_cast<ushort4*>(dst)[d4] = o;
}

// ---------------- GEMM (f32 out): C = A[M][K] x B[N][K]^T ----------------
// 128x128 tile, BK=64, 4 waves (2x2). 2-PHASE pipeline: STAGE(t+1) before
// compute(t); ONE barrier per K-step. Double-buffered LDS.
__global__ __launch_bounds__(256) void k_gemm_bt(const ushort* __restrict__ A,
                                                 const ushort* __restrict__ B,
                                                 float* __restrict__ C,
                                                 int M, int N, int K){
  __shared__ ushort As[2][128*64];
  __shared__ ushort Bs[2][128*64];
  const int tid = threadIdx.x, lane = tid & 63, wid = tid >> 6;
  const int bm = blockIdx.y * 128, bn = blockIdx.x * 128;
  const int wr = wid >> 1, wc = wid & 1;
  const int l15 = lane & 15, u = lane >> 4;

  const int srow = wid*32 + (lane >> 3);
  const int scol = ((lane & 7) ^ (lane >> 3)) * 8;   // pre-swizzled k-chunk
  const ushort* Abase = A + (size_t)(bm + srow) * K + scol;
  const ushort* Bbase = B + (size_t)(bn + srow) * K + scol;

  auto STAGE = [&](int buf, int k0){
#pragma unroll
    for (int c = 0; c < 4; c++){
      gl_lds16(Abase + k0 + (size_t)c*8*K, &As[buf][(wid*32 + c*8)*64]);
      gl_lds16(Bbase + k0 + (size_t)c*8*K, &Bs[buf][(wid*32 + c*8)*64]);
    }
  };

  f32x4 acc[4][4] = {};
  const int NT = K >> 6;

  STAGE(0, 0);
  __syncthreads();

  for (int t = 0; t < NT; t++){
    const int cur = t & 1;
    if (t + 1 < NT) STAGE(cur ^ 1, (t + 1) << 6);

#pragma unroll
    for (int kc = 0; kc < 2; kc++){
      bf16x8 af[4], bfr[4];
#pragma unroll
      for (int m = 0; m < 4; m++){
        int row = wr*64 + m*16 + l15;
        af[m] = *reinterpret_cast<const bf16x8*>(&As[cur][row*64 + (((kc*4+u) ^ (row&7))*8)]);
      }
#pragma unroll
      for (int n = 0; n < 4; n++){
        int row = wc*64 + n*16 + l15;
        bfr[n] = *reinterpret_cast<const bf16x8*>(&Bs[cur][row*64 + (((kc*4+u) ^ (row&7))*8)]);
      }
      __builtin_amdgcn_s_setprio(1);
#pragma unroll
      for (int m = 0; m < 4; m++)
#pragma unroll
        for (int n = 0; n < 4; n++)
          acc[m][n] = __builtin_amdgcn_mfma_f32_16x16x32_bf16(af[m], bfr[n], acc[m][n], 0, 0, 0);
      __builtin_amdgcn_s_setprio(0);
    }

    __syncthreads();
  }

#pragma unroll
  for (int m = 0; m < 4; m++)
#pragma unroll
    for (int n = 0; n < 4; n++)
#pragma unroll
      for (int j = 0; j < 4; j++){
        int row = bm + wr*64 + m*16 + u*4 + j;
        int col = bn + wc*64 + n*16 + l15;
        C[(size_t)row * N + col] = acc[m][n][j];
      }
}

// ---------------- GEMM (bf16 out): qkvc = xb x wcat^T ----------------
__global__ __launch_bounds__(256) void k_gemm_btc(const ushort* __restrict__ A,
                                                  const ushort* __restrict__ B,
                                                  ushort* __restrict__ C,
                                                  int M, int N, int K){
  __shared__ ushort As[2][128*64];
  __shared__ ushort Bs[2][128*64];
  const int tid = threadIdx.x, lane = tid & 63, wid = tid >> 6;
  const int bm = blockIdx.y * 128, bn = blockIdx.x * 128;
  const int wr = wid >> 1, wc = wid & 1;
  const int l15 = lane & 15, u = lane >> 4;

  const int srow = wid*32 + (lane >> 3);
  const int scol = ((lane & 7) ^ (lane >> 3)) * 8;
  const ushort* Abase = A + (size_t)(bm + srow) * K + scol;
  const ushort* Bbase = B + (size_t)(bn + srow) * K + scol;

  auto STAGE = [&](int buf, int k0){
#pragma unroll
    for (int c = 0; c < 4; c++){
      gl_lds16(Abase + k0 + (size_t)c*8*K, &As[buf][(wid*32 + c*8)*64]);
      gl_lds16(Bbase + k0 + (size_t)c*8*K, &Bs[buf][(wid*32 + c*8)*64]);
    }
  };

  f32x4 acc[4][4] = {};
  const int NT = K >> 6;

  STAGE(0, 0);
  __syncthreads();

  for (int t = 0; t < NT; t++){
    const int cur = t & 1;
    if (t + 1 < NT) STAGE(cur ^ 1, (t + 1) << 6);

#pragma unroll
    for (int kc = 0; kc < 2; kc++){
      bf16x8 af[4], bfr[4];
#pragma unroll
      for (int m = 0; m < 4; m++){
        int row = wr*64 + m*16 + l15;
        af[m] = *reinterpret_cast<const bf16x8*>(&As[cur][row*64 + (((kc*4+u) ^ (row&7))*8)]);
      }
#pragma unroll
      for (int n = 0; n < 4; n++){
        int row = wc*64 + n*16 + l15;
        bfr[n] = *reinterpret_cast<const bf16x8*>(&Bs[cur][row*64 + (((kc*4+u) ^ (row&7))*8)]);
      }
      __builtin_amdgcn_s_setprio(1);
#pragma unroll
      for (int m = 0; m < 4; m++)
#pragma unroll
        for (int n = 0; n < 4; n++)
          acc[m][n] = __builtin_amdgcn_mfma_f32_16x16x32_bf16(af[m], bfr[n], acc[m][n], 0, 0, 0);
      __builtin_amdgcn_s_setprio(0);
    }

    __syncthreads();
  }

#pragma unroll
  for (int m = 0; m < 4; m++)
#pragma unroll
    for (int n = 0; n < 4; n++)
#pragma unroll
      for (int j = 0; j < 4; j++){
        int row = bm + wr*64 + m*16 + u*4 + j;
        int col = bn + wc*64 + n*16 + l15;
        C[(size_t)row * N + col] = bf(acc[m][n][j]);
      }
}

// ---------------- fused RMSNorm + RoPE (bf16 in, bf16 out; q, k only) -------
__global__ __launch_bounds__(256) void k_normrope(const ushort* __restrict__ qkvc,
                                                  const float* __restrict__ cosp,
                                                  const float* __restrict__ sinp,
                                                  const float* __restrict__ qg,
                                                  const float* __restrict__ kg,
                                                  ushort* __restrict__ qb,
                                                  ushort* __restrict__ kb){
  const int s = blockIdx.x;
  const int tid = threadIdx.x, lane = tid & 63, wid = tid >> 6;
  const ushort* row = qkvc + (size_t)s * NQKV;
  const float cs = cosp[s*HDIM + lane];
  const float sn = sinp[s*HDIM + lane];

  for (int hidx = wid; hidx < 40; hidx += 4){
    const bool isq = hidx < 32;
    const int col = isq ? hidx*64 : 2048 + (hidx-32)*64;
    float x = b2f(row[col + lane]);
    float ss = x * x;
#pragma unroll
    for (int m = 1; m < 64; m <<= 1) ss += __shfl_xor(ss, m);
    float r = rsqrtf(ss * (1.0f/64.0f) + 1e-6f);
    float y = x * r * (isq ? qg : kg)[lane];
    float p = __shfl_xor(y, 32);
    float out = y * cs + (lane < 32 ? -p : p) * sn;
    if (isq) qb[(size_t)s*2048 + hidx*64 + lane] = bf(out * SCALE2);
    else     kb[(size_t)s*512 + (hidx-32)*64 + lane] = bf(out);
  }
}

// ---------------- V transpose: qkvc v-section bf16 -> vtb (slot-ordered) ----
__global__ __launch_bounds__(256) void k_vtrans(const ushort* __restrict__ qkvc,
                                                ushort* __restrict__ vtb){
  __shared__ ushort tile[64][68];     // [d][s], pad 68
  const int g = blockIdx.x >> 5, st = blockIdx.x & 31;
  const int tid = threadIdx.x;
#pragma unroll
  for (int i = 0; i < 4; i++){
    int idx = i*256 + tid;
    int r = idx >> 4, c4 = idx & 15;
    ushort4 v = *reinterpret_cast<const ushort4*>(
        qkvc + (size_t)(st*64 + r)*NQKV + 2560 + g*64 + c4*4);
    tile[c4*4+0][r] = v.x;
    tile[c4*4+1][r] = v.y;
    tile[c4*4+2][r] = v.z;
    tile[c4*4+3][r] = v.w;
  }
  __syncthreads();
#pragma unroll
  for (int i = 0; i < 4; i++){
    int idx = i*256 + tid;
    int d = idx >> 4, s4 = idx & 15;
    // sigma: key chunk s4=(kb,u) -> PV-slot-ordered position
    int pos4 = (s4 >> 3)*32 + (s4 & 3)*8 + ((s4 >> 2) & 1)*4;
    ushort4 o = *reinterpret_cast<const ushort4*>(&tile[d][s4*4]);
    *reinterpret_cast<ushort4*>(vtb + (size_t)(g*64 + d)*SEQ + st*64 + pos4) = o;
  }
}

// ------------- causal flash GQA attention, 8-wave blocks, split-KV ---------
// Block = (head, 128-row q-tile, KV-half). 512 thr = 8 waves x 16 q-rows;
// one staged 64-key K/V tile shared by all 8 waves (LDS 32 KB).
// Grid 1024 x 512 thr = exact whole-GPU fit (4 blocks/CU); per-CU part
// lengths (j+1, 16-j, j+1, 16-j) sum to 34 for EVERY CU -> perfect balance.
// part0 = tiles [0,qt+1) (never masked), part1 = [qt+1,2qt+2) (diagonal).
// Fully-masked waves in part1 are zeroed by the defer-max rescale (al=0)
// or by k_comb (weight 2^(m-mmax)=0 with m=-1e30).
__global__ __launch_bounds__(512) void k_attn(const ushort* __restrict__ qbuf,
                                              const ushort* __restrict__ kbuf,
                                              const ushort* __restrict__ vtb,
                                              ushort* __restrict__ op,
                                              float2* __restrict__ ml){
  __shared__ ushort Kd[2][64*64];       // swizzled K tiles   (16 KB)
  __shared__ ushort Vd[2][64*64];       // swizzled V^T tiles (16 KB)

  const int bx = blockIdx.x;
  const int cu = bx & 255, slot = bx >> 8;
  const int h = cu >> 3, j = cu & 7;
  const int qt   = (slot & 1) ? (15 - j) : j;
  const int part = slot >> 1;
  const int g = h >> 2;
  const int t0 = part ? (qt + 1)   : 0;
  const int t1 = part ? (2*qt + 2) : (qt + 1);
  const int tid = threadIdx.x, lane = tid & 63, wid = tid >> 6;   // wid 0..7
  const int l15 = lane & 15, u = lane >> 4;
  const int q0 = qt*128 + wid*16;       // wave's first q-row

  // Q fragments (B-operand: col=l15 -> q-row)
  bf16x8 qf[2];
#pragma unroll
  for (int kc = 0; kc < 2; kc++)
    qf[kc] = *reinterpret_cast<const bf16x8*>(
        qbuf + (size_t)(q0 + l15)*2048 + h*64 + kc*32 + u*8);

  f32x4 o[4] = {};                      // O^T: o[d0][j] = O[q=l15][d0*16+u*4+j]
  float mrun = -1e30f;
  float lrun = 0.f;                     // per-lane partial (reduced at end)

  // hoisted swizzled LDS byte-offsets (loop-invariant, static-indexed)
  int koff[8], voff[8];
#pragma unroll
  for (int kb = 0; kb < 4; kb++)
#pragma unroll
    for (int kc = 0; kc < 2; kc++){
      int keyl = kb*16 + l15;
      koff[kb*2+kc] = (keyl*64 + (((kc*4+u) ^ (keyl&7))*8)) * 2;
    }
#pragma unroll
  for (int kc = 0; kc < 2; kc++)
#pragma unroll
    for (int d0 = 0; d0 < 4; d0++){
      int vrow = d0*16 + l15;
      voff[kc*4+d0] = (vrow*64 + (((kc*4+u) ^ (vrow&7))*8)) * 2;
    }

  // staging: 8 waves x 1 chunk (8 rows x 128B) each for K and V
  const int srow = wid*8 + (lane >> 3);
  const int scol = ((lane & 7) ^ (lane >> 3)) * 8;
  const ushort* ksrc0 = kbuf + (size_t)srow*512 + g*64 + scol;
  const ushort* vsrc0 = vtb  + (size_t)(g*64 + srow)*SEQ + scol;

  auto STAGE = [&](int buf, int t){
    gl_lds16(ksrc0 + (size_t)t*64*512, &Kd[buf][wid*512]);
    gl_lds16(vsrc0 + t*64,             &Vd[buf][wid*512]);
  };

  STAGE(0, t0);
  __syncthreads();   // drains vmcnt(0): first tile visible

  for (int t = t0; t < t1; t++){
    const int cur = (t - t0) & 1;
    if (t + 1 < t1) STAGE(cur ^ 1, t + 1);

    const char* KB = (const char*)Kd + cur*8192;
    const char* VB = (const char*)Vd + cur*8192;
    const bool full = (t*64 + 63) <= q0;

    // ---- S^T = mfma(K, Q) ----
    f32x4 st[4];
#pragma unroll
    for (int kb = 0; kb < 4; kb++){
      const int key0 = t*64 + kb*16;
      if (key0 <= q0 + 15){
        bf16x8 kf0 = *reinterpret_cast<const bf16x8*>(KB + koff[kb*2]);
        bf16x8 kf1 = *reinterpret_cast<const bf16x8*>(KB + koff[kb*2+1]);
        f32x4 a = {};
        a = __builtin_amdgcn_mfma_f32_16x16x32_bf16(kf0, qf[0], a, 0, 0, 0);
        a = __builtin_amdgcn_mfma_f32_16x16x32_bf16(kf1, qf[1], a, 0, 0, 0);
        st[kb] = a;
      } else {
        st[kb] = (f32x4){-1e30f, -1e30f, -1e30f, -1e30f};
      }
    }
    if (!full){
      const int keyb = t*64 + u*4;
      const int qr = q0 + l15;
#pragma unroll
      for (int kb = 0; kb < 4; kb++)
#pragma unroll
        for (int j = 0; j < 4; j++)
          st[kb][j] = (keyb + kb*16 + j > qr) ? -1e30f : st[kb][j];
    }

    // ---- online softmax (defer-max) ----
    {
      f32x4 mx = st[0];
#pragma unroll
      for (int kb = 1; kb < 4; kb++)
#pragma unroll
        for (int j = 0; j < 4; j++) mx[j] = fmaxf(mx[j], st[kb][j]);
      float tml = fmaxf(fmaxf(mx[0], mx[1]), fmaxf(mx[2], mx[3]));
      if (__any(tml > mrun + THR2)){
        float tm = fmaxf(tml, __shfl_xor(tml, 16));
        tm = fmaxf(tm, __shfl_xor(tm, 32));
        float mn = fmaxf(mrun, tm);
        float al = exp2f(mrun - mn);
        mrun = mn;
        lrun *= al;
#pragma unroll
        for (int d0 = 0; d0 < 4; d0++)
#pragma unroll
          for (int j = 0; j < 4; j++) o[d0][j] *= al;
      }
#pragma unroll
      for (int kb = 0; kb < 4; kb++)
#pragma unroll
        for (int j = 0; j < 4; j++){
          float p = exp2f(st[kb][j] - mrun);
          st[kb][j] = p;
          lrun += p;
        }
    }

    // ---- O^T += V^T-frag x P-frag; P packed in-lane (cvt_pk) ----
    __builtin_amdgcn_s_setprio(1);
#pragma unroll
    for (int kc = 0; kc < 2; kc++){
      union { uint32_t w[4]; bf16x8 v; } pb;
      asm("v_cvt_pk_bf16_f32 %0, %1, %2" : "=v"(pb.w[0]) : "v"(st[2*kc  ][0]), "v"(st[2*kc  ][1]));
      asm("v_cvt_pk_bf16_f32 %0, %1, %2" : "=v"(pb.w[1]) : "v"(st[2*kc  ][2]), "v"(st[2*kc  ][3]));
      asm("v_cvt_pk_bf16_f32 %0, %1, %2" : "=v"(pb.w[2]) : "v"(st[2*kc+1][0]), "v"(st[2*kc+1][1]));
      asm("v_cvt_pk_bf16_f32 %0, %1, %2" : "=v"(pb.w[3]) : "v"(st[2*kc+1][2]), "v"(st[2*kc+1][3]));
#pragma unroll
      for (int d0 = 0; d0 < 4; d0++){
        bf16x8 vb8 = *reinterpret_cast<const bf16x8*>(VB + voff[kc*4+d0]);
        o[d0] = __builtin_amdgcn_mfma_f32_16x16x32_bf16(vb8, pb.v, o[d0], 0, 0, 0);
      }
    }
    __builtin_amdgcn_s_setprio(0);

    __syncthreads();  // publishes tile t+1 + protects buffer reuse
  }

  // epilogue: reduce lrun once; store NORMALIZED partial O + (m,l)
  {
    float lt = lrun + __shfl_xor(lrun, 16);
    lt += __shfl_xor(lt, 32);
    float inv = lt > 0.f ? 1.0f / lt : 0.f;
    const size_t ridx = (size_t)part*65536 + h*2048 + (q0 + l15);
#pragma unroll
    for (int d0 = 0; d0 < 4; d0++){
      ushort4 w;
      w.x = bf(o[d0][0] * inv); w.y = bf(o[d0][1] * inv);
      w.z = bf(o[d0][2] * inv); w.w = bf(o[d0][3] * inv);
      *reinterpret_cast<ushort4*>(&op[ridx*64 + d0*16 + u*4]) = w;
    }
    if (lane < 16) ml[ridx] = make_float2(mrun, lt);
  }
}

// ---------------- combine two KV-half partials -> ctx bf16 ----------------
// thread = (h, row, quarter of 16 dims). 1024 blocks x 256 threads.
__global__ __launch_bounds__(256) void k_comb(const ushort* __restrict__ op,
                                              const float2* __restrict__ ml,
                                              ushort* __restrict__ ctx){
  const int tq = blockIdx.x*256 + threadIdx.x;
  const int q = tq & 3, row = (tq >> 2) & 2047, h = tq >> 13;
  const int idx = h*2048 + row;
  float2 a = ml[idx], b = ml[idx + 65536];
  float m = fmaxf(a.x, b.x);
  float w0 = exp2f(a.x - m) * a.y;
  float w1 = exp2f(b.x - m) * b.y;
  float inv = 1.0f / (w0 + w1);
  w0 *= inv; w1 *= inv;
  const ushort4* p0 = reinterpret_cast<const ushort4*>(op + (size_t)idx*64 + q*16);
  const ushort4* p1 = reinterpret_cast<const ushort4*>(op + ((size_t)idx + 65536)*64 + q*16);
  ushort* dst = ctx + (size_t)row*2048 + h*64 + q*16;
#pragma unroll
  for (int i = 0; i < 4; i++){
    ushort4 x0 = p0[i], x1 = p1[i];
    ushort4 w;
    w.x = bf(w0*b2f(x0.x) + w1*b2f(x1.x));
    w.y = bf(w0*b2f(x0.y) + w1*b2f(x1.y));
    w.z = bf(w0*b2f(x0.z) + w1*b2f(x1.z));
    w.w = bf(w0*b2f(x0.w) + w1*b2f(x1.w));
    reinterpret_cast<ushort4*>(dst)[i] = w;
  }
}

// ---------------- launcher ----------------
extern "C" void kernel_launch(void* const* d_in, const int* in_sizes, int n_in,
                              void* d_out, int out_size, void* d_ws, size_t ws_size,
                              hipStream_t stream){
  const float* x    = (const float*)d_in[0];
  // d_in[1] = mask (unused; causal mask computed analytically)
  const float* cosp = (const float*)d_in[2];
  const float* sinp = (const float*)d_in[3];
  const float* wq   = (const float*)d_in[4];
  const float* wk   = (const float*)d_in[5];
  const float* wv   = (const float*)d_in[6];
  const float* wo   = (const float*)d_in[7];
  const float* qg   = (const float*)d_in[8];
  const float* kg   = (const float*)d_in[9];
  float* out = (float*)d_out;

  char* ws = (char*)d_ws;
  ushort* xb   = (ushort*)(ws);                    //  8 MB  x bf16
  ushort* wcat = (ushort*)(ws + 8388608);          // 12 MB  [wq;wk;wv] bf16
  ushort* wob  = (ushort*)(ws + 20971520);         //  8 MB  wo bf16
  ushort* qkvc = (ushort*)(ws + 29360128);         // 12 MB  qkv bf16 [2048][3072]
  ushort* qb   = (ushort*)(ws + 41943040);         //  8 MB  q bf16 (pre-scaled)
  ushort* kb   = (ushort*)(ws + 50331648);         //  2 MB  k bf16 [2048][512]
  ushort* vtb  = (ushort*)(ws + 52428800);         //  2 MB  v^T bf16 (slot-ordered)
  ushort* ctxb = (ushort*)(ws + 54525952);         //  8 MB  ctx bf16
  // partials OVERLAY xb+wcat (dead after k_gemm_btc):
  ushort* op   = (ushort*)(ws);                    // 16 MB  [2][32][2048][64] bf16
  float2* ml   = (float2*)(ws + 16777216);         //  1 MB  [2][32][2048] float2
  // total 62,914,560 bytes

  k_cvt_all<<<14336, 256, 0, stream>>>(x, wq, wk, wv, wo, xb, wcat, wob);
  k_gemm_btc<<<dim3(24, 16), 256, 0, stream>>>(xb, wcat, qkvc, 2048, 3072, 2048);
  k_normrope<<<2048, 256, 0, stream>>>(qkvc, cosp, sinp, qg, kg, qb, kb);
  k_vtrans<<<256, 256, 0, stream>>>(qkvc, vtb);
  k_attn<<<1024, 512, 0, stream>>>(qb, kb, vtb, op, ml);
  k_comb<<<1024, 256, 0, stream>>>(op, ml, ctxb);
  k_gemm_bt<<<dim3(16, 16), 256, 0, stream>>>(ctxb, wob, out, 2048, 2048, 2048);
}

// Round 13
// 138.778 us; speedup vs baseline: 1.1107x; 1.1107x over previous
//
#include <hip/hip_runtime.h>
#include <stdint.h>

// Problem constants (fixed-shape problem)
#define SEQ    2048
#define DMODEL 2048
#define NHEAD  32
#define NKV    8
#define HDIM   64
#define NQKV   3072   // 2048 q + 512 k + 512 v

typedef __bf16 bf16x8 __attribute__((ext_vector_type(8)));
typedef float  f32x4  __attribute__((ext_vector_type(4)));

#define SCALE2 0.180336880f   // 0.125 * log2(e): scores land in log2 domain
#define THR2   12.0f          // defer-max threshold (log2 domain); P <= 2^12

__device__ __forceinline__ ushort bf(float f){
  __bf16 h = (__bf16)f;               // native RNE convert on gfx950
  return __builtin_bit_cast(unsigned short, h);
}
__device__ __forceinline__ float b2f(ushort v){
  union { uint32_t u; float f; } a; a.u = ((uint32_t)v) << 16; return a.f;
}

__device__ __forceinline__ void gl_lds16(const void* g, void* l){
  __builtin_amdgcn_global_load_lds(
      (const __attribute__((address_space(1))) uint32_t*)g,
      (__attribute__((address_space(3))) uint32_t*)l, 16, 0, 0);
}

// ------------- all f32->bf16 converts in one kernel -------------
__global__ __launch_bounds__(256) void k_cvt_all(const float* __restrict__ x,
                                                 const float* __restrict__ wq,
                                                 const float* __restrict__ wk,
                                                 const float* __restrict__ wv,
                                                 const float* __restrict__ wo,
                                                 ushort* __restrict__ xb,
                                                 ushort* __restrict__ wcat,
                                                 ushort* __restrict__ wob){
  int i = blockIdx.x * 256 + threadIdx.x;
  const float* src; ushort* dst; int s4; int d4;
  if (i < 1048576)      { src = x;  dst = xb;   s4 = i;           d4 = s4; }
  else if (i < 2097152) { src = wq; dst = wcat; s4 = i - 1048576; d4 = s4; }
  else if (i < 2359296) { src = wk; dst = wcat; s4 = i - 2097152; d4 = s4 + 1048576; }
  else if (i < 2621440) { src = wv; dst = wcat; s4 = i - 2359296; d4 = s4 + 1310720; }
  else                  { src = wo; dst = wob;  s4 = i - 2621440; d4 = s4; }
  float4 v = reinterpret_cast<const float4*>(src)[s4];
  ushort4 o;
  o.x = bf(v.x); o.y = bf(v.y); o.z = bf(v.z); o.w = bf(v.w);
  reinterpret_cast<ushort4*>(dst)[d4] = o;
}

// ---------------- GEMM (f32 out): C = A[M][K] x B[N][K]^T ----------------
// Tile 128x64, BK=64, 4 waves (2x2; per-wave 64x32). Grid (N/64, M/128) =
// 512 blocks = exactly 2/CU (no quantization waste), LDS 49KB -> both
// resident, 8 waves/CU. 2-PHASE pipeline, one barrier per K-step.
__global__ __launch_bounds__(256) void k_gemm_bt(const ushort* __restrict__ A,
                                                 const ushort* __restrict__ B,
                                                 float* __restrict__ C,
                                                 int M, int N, int K){
  __shared__ ushort As[2][128*64];
  __shared__ ushort Bs[2][64*64];
  const int tid = threadIdx.x, lane = tid & 63, wid = tid >> 6;
  const int bm = blockIdx.y * 128, bn = blockIdx.x * 64;
  const int wr = wid >> 1, wc = wid & 1;
  const int l15 = lane & 15, u = lane >> 4;

  const int crow = lane >> 3;                       // row within 8-row chunk
  const int scol = ((lane & 7) ^ crow) * 8;         // pre-swizzled 16B slot
  const ushort* Abase = A + (size_t)(bm + wid*32 + crow) * K + scol;
  const ushort* Bbase = B + (size_t)(bn + wid*16 + crow) * K + scol;

  auto STAGE = [&](int buf, int k0){
#pragma unroll
    for (int c = 0; c < 4; c++)
      gl_lds16(Abase + k0 + (size_t)c*8*K, &As[buf][(wid*32 + c*8)*64]);
#pragma unroll
    for (int c = 0; c < 2; c++)
      gl_lds16(Bbase + k0 + (size_t)c*8*K, &Bs[buf][(wid*16 + c*8)*64]);
  };

  f32x4 acc[4][2] = {};
  const int NT = K >> 6;

  STAGE(0, 0);
  __syncthreads();

  for (int t = 0; t < NT; t++){
    const int cur = t & 1;
    if (t + 1 < NT) STAGE(cur ^ 1, (t + 1) << 6);

#pragma unroll
    for (int kc = 0; kc < 2; kc++){
      bf16x8 af[4], bfr[2];
#pragma unroll
      for (int m = 0; m < 4; m++){
        int row = wr*64 + m*16 + l15;
        af[m] = *reinterpret_cast<const bf16x8*>(&As[cur][row*64 + (((kc*4+u) ^ (row&7))*8)]);
      }
#pragma unroll
      for (int n = 0; n < 2; n++){
        int row = wc*32 + n*16 + l15;
        bfr[n] = *reinterpret_cast<const bf16x8*>(&Bs[cur][row*64 + (((kc*4+u) ^ (row&7))*8)]);
      }
      __builtin_amdgcn_s_setprio(1);
#pragma unroll
      for (int m = 0; m < 4; m++)
#pragma unroll
        for (int n = 0; n < 2; n++)
          acc[m][n] = __builtin_amdgcn_mfma_f32_16x16x32_bf16(af[m], bfr[n], acc[m][n], 0, 0, 0);
      __builtin_amdgcn_s_setprio(0);
    }

    __syncthreads();
  }

#pragma unroll
  for (int m = 0; m < 4; m++)
#pragma unroll
    for (int n = 0; n < 2; n++)
#pragma unroll
      for (int j = 0; j < 4; j++){
        int row = bm + wr*64 + m*16 + u*4 + j;
        int col = bn + wc*32 + n*16 + l15;
        C[(size_t)row * N + col] = acc[m][n][j];
      }
}

// ---------------- GEMM (bf16 out): qkvc = xb x wcat^T ----------------
// Tile 128x96, BK=64, 4 waves (2x2; per-wave 64x48). Grid (3072/96, 2048/128)
// = (32,16) = 512 blocks = exactly 2/CU, LDS 57KB -> both resident.
__global__ __launch_bounds__(256) void k_gemm_btc(const ushort* __restrict__ A,
                                                  const ushort* __restrict__ B,
                                                  ushort* __restrict__ C,
                                                  int M, int N, int K){
  __shared__ ushort As[2][128*64];
  __shared__ ushort Bs[2][96*64];
  const int tid = threadIdx.x, lane = tid & 63, wid = tid >> 6;
  const int bm = blockIdx.y * 128, bn = blockIdx.x * 96;
  const int wr = wid >> 1, wc = wid & 1;
  const int l15 = lane & 15, u = lane >> 4;

  const int crow = lane >> 3;
  const int scol = ((lane & 7) ^ crow) * 8;
  const ushort* Abase = A + (size_t)(bm + wid*32 + crow) * K + scol;
  const ushort* Bbase = B + (size_t)(bn + wid*24 + crow) * K + scol;

  auto STAGE = [&](int buf, int k0){
#pragma unroll
    for (int c = 0; c < 4; c++)
      gl_lds16(Abase + k0 + (size_t)c*8*K, &As[buf][(wid*32 + c*8)*64]);
#pragma unroll
    for (int c = 0; c < 3; c++)
      gl_lds16(Bbase + k0 + (size_t)c*8*K, &Bs[buf][(wid*24 + c*8)*64]);
  };

  f32x4 acc[4][3] = {};
  const int NT = K >> 6;

  STAGE(0, 0);
  __syncthreads();

  for (int t = 0; t < NT; t++){
    const int cur = t & 1;
    if (t + 1 < NT) STAGE(cur ^ 1, (t + 1) << 6);

#pragma unroll
    for (int kc = 0; kc < 2; kc++){
      bf16x8 af[4], bfr[3];
#pragma unroll
      for (int m = 0; m < 4; m++){
        int row = wr*64 + m*16 + l15;
        af[m] = *reinterpret_cast<const bf16x8*>(&As[cur][row*64 + (((kc*4+u) ^ (row&7))*8)]);
      }
#pragma unroll
      for (int n = 0; n < 3; n++){
        int row = wc*48 + n*16 + l15;
        bfr[n] = *reinterpret_cast<const bf16x8*>(&Bs[cur][row*64 + (((kc*4+u) ^ (row&7))*8)]);
      }
      __builtin_amdgcn_s_setprio(1);
#pragma unroll
      for (int m = 0; m < 4; m++)
#pragma unroll
        for (int n = 0; n < 3; n++)
          acc[m][n] = __builtin_amdgcn_mfma_f32_16x16x32_bf16(af[m], bfr[n], acc[m][n], 0, 0, 0);
      __builtin_amdgcn_s_setprio(0);
    }

    __syncthreads();
  }

#pragma unroll
  for (int m = 0; m < 4; m++)
#pragma unroll
    for (int n = 0; n < 3; n++)
#pragma unroll
      for (int j = 0; j < 4; j++){
        int row = bm + wr*64 + m*16 + u*4 + j;
        int col = bn + wc*48 + n*16 + l15;
        C[(size_t)row * N + col] = bf(acc[m][n][j]);
      }
}

// ---------------- fused RMSNorm + RoPE (bf16 in, bf16 out; q, k only) -------
__global__ __launch_bounds__(256) void k_normrope(const ushort* __restrict__ qkvc,
                                                  const float* __restrict__ cosp,
                                                  const float* __restrict__ sinp,
                                                  const float* __restrict__ qg,
                                                  const float* __restrict__ kg,
                                                  ushort* __restrict__ qb,
                                                  ushort* __restrict__ kb){
  const int s = blockIdx.x;
  const int tid = threadIdx.x, lane = tid & 63, wid = tid >> 6;
  const ushort* row = qkvc + (size_t)s * NQKV;
  const float cs = cosp[s*HDIM + lane];
  const float sn = sinp[s*HDIM + lane];

  for (int hidx = wid; hidx < 40; hidx += 4){
    const bool isq = hidx < 32;
    const int col = isq ? hidx*64 : 2048 + (hidx-32)*64;
    float x = b2f(row[col + lane]);
    float ss = x * x;
#pragma unroll
    for (int m = 1; m < 64; m <<= 1) ss += __shfl_xor(ss, m);
    float r = rsqrtf(ss * (1.0f/64.0f) + 1e-6f);
    float y = x * r * (isq ? qg : kg)[lane];
    float p = __shfl_xor(y, 32);
    float out = y * cs + (lane < 32 ? -p : p) * sn;
    if (isq) qb[(size_t)s*2048 + hidx*64 + lane] = bf(out * SCALE2);
    else     kb[(size_t)s*512 + (hidx-32)*64 + lane] = bf(out);
  }
}

// ---------------- V transpose: qkvc v-section bf16 -> vtb (slot-ordered) ----
__global__ __launch_bounds__(256) void k_vtrans(const ushort* __restrict__ qkvc,
                                                ushort* __restrict__ vtb){
  __shared__ ushort tile[64][68];     // [d][s], pad 68
  const int g = blockIdx.x >> 5, st = blockIdx.x & 31;
  const int tid = threadIdx.x;
#pragma unroll
  for (int i = 0; i < 4; i++){
    int idx = i*256 + tid;
    int r = idx >> 4, c4 = idx & 15;
    ushort4 v = *reinterpret_cast<const ushort4*>(
        qkvc + (size_t)(st*64 + r)*NQKV + 2560 + g*64 + c4*4);
    tile[c4*4+0][r] = v.x;
    tile[c4*4+1][r] = v.y;
    tile[c4*4+2][r] = v.z;
    tile[c4*4+3][r] = v.w;
  }
  __syncthreads();
#pragma unroll
  for (int i = 0; i < 4; i++){
    int idx = i*256 + tid;
    int d = idx >> 4, s4 = idx & 15;
    // sigma: key chunk s4=(kb,u) -> PV-slot-ordered position
    int pos4 = (s4 >> 3)*32 + (s4 & 3)*8 + ((s4 >> 2) & 1)*4;
    ushort4 o = *reinterpret_cast<const ushort4*>(&tile[d][s4*4]);
    *reinterpret_cast<ushort4*>(vtb + (size_t)(g*64 + d)*SEQ + st*64 + pos4) = o;
  }
}

// ---------------- causal flash GQA attention, SPLIT-KV (2 parts) ----------
// Block = (head, 64-row q-tile, KV-half). n=qt+1 tiles split [0,h1)/[h1,n),
// h1=(n+1)/2. Grid 2048 (qt descending = LPT): 8 blocks/CU dispatched,
// 5 resident (LDS 32KB x 5 = 160KB), 3 queued -> backfill sustains occupancy.
// Writes normalized partial O (bf16) + (m,l) f32; k_comb merges.
__global__ __launch_bounds__(256) void k_attn(const ushort* __restrict__ qbuf,
                                              const ushort* __restrict__ kbuf,
                                              const ushort* __restrict__ vtb,
                                              ushort* __restrict__ op,
                                              float2* __restrict__ ml){
  __shared__ ushort Kd[2][64*64];       // swizzled K tiles   (16 KB)
  __shared__ ushort Vd[2][64*64];       // swizzled V^T tiles (16 KB)

  const int bx = blockIdx.x;
  const int qt   = 31 - (bx >> 6);      // descending: longest parts first
  const int part = (bx >> 5) & 1;
  const int h    = bx & 31;
  const int g = h >> 2;
  const int n  = qt + 1;
  const int h1 = (n + 1) >> 1;
  const int t0 = part ? h1 : 0;
  const int t1 = part ? n  : h1;
  const int tid = threadIdx.x, lane = tid & 63, wid = tid >> 6;
  const int l15 = lane & 15, u = lane >> 4;
  const int q0 = qt*64 + wid*16;        // wave's first q-row

  // Q fragments (B-operand: col=l15 -> q-row)
  bf16x8 qf[2];
#pragma unroll
  for (int kc = 0; kc < 2; kc++)
    qf[kc] = *reinterpret_cast<const bf16x8*>(
        qbuf + (size_t)(q0 + l15)*2048 + h*64 + kc*32 + u*8);

  f32x4 o[4] = {};                      // O^T: o[d0][j] = O[q=l15][d0*16+u*4+j]
  float mrun = -1e30f;
  float lrun = 0.f;                     // per-lane partial (reduced at end)

  // hoisted swizzled LDS byte-offsets (loop-invariant, static-indexed)
  int koff[8], voff[8];
#pragma unroll
  for (int kb = 0; kb < 4; kb++)
#pragma unroll
    for (int kc = 0; kc < 2; kc++){
      int keyl = kb*16 + l15;
      koff[kb*2+kc] = (keyl*64 + (((kc*4+u) ^ (keyl&7))*8)) * 2;
    }
#pragma unroll
  for (int kc = 0; kc < 2; kc++)
#pragma unroll
    for (int d0 = 0; d0 < 4; d0++){
      int vrow = d0*16 + l15;
      voff[kc*4+d0] = (vrow*64 + (((kc*4+u) ^ (vrow&7))*8)) * 2;
    }

  // staging: 8 chunks of 1KB per tile; wave does 2 K + 2 V
  const int srow = wid*16 + (lane >> 3);
  const int scol = ((lane & 7) ^ (lane >> 3)) * 8;
  const ushort* ksrc0 = kbuf + (size_t)srow*512 + g*64 + scol;
  const ushort* vsrc0 = vtb  + (size_t)(g*64 + srow)*SEQ + scol;

  auto STAGE = [&](int buf, int t){
    const ushort* ks = ksrc0 + (size_t)t*64*512;
    gl_lds16(ks,         &Kd[buf][wid*1024]);
    gl_lds16(ks + 8*512, &Kd[buf][wid*1024 + 512]);
    const ushort* vs = vsrc0 + t*64;
    gl_lds16(vs,          &Vd[buf][wid*1024]);
    gl_lds16(vs + 8*SEQ,  &Vd[buf][wid*1024 + 512]);
  };

  if (t0 < t1){
    STAGE(0, t0);
    __syncthreads();   // drains vmcnt(0): first tile visible

    for (int t = t0; t < t1; t++){
      const int cur = (t - t0) & 1;
      if (t + 1 < t1) STAGE(cur ^ 1, t + 1);

      const char* KB = (const char*)Kd + cur*8192;
      const char* VB = (const char*)Vd + cur*8192;
      const bool full = (t*64 + 63) <= q0;

      // ---- S^T = mfma(K, Q) ----
      f32x4 st[4];
#pragma unroll
      for (int kb = 0; kb < 4; kb++){
        const int key0 = t*64 + kb*16;
        if (key0 <= q0 + 15){
          bf16x8 kf0 = *reinterpret_cast<const bf16x8*>(KB + koff[kb*2]);
          bf16x8 kf1 = *reinterpret_cast<const bf16x8*>(KB + koff[kb*2+1]);
          f32x4 a = {};
          a = __builtin_amdgcn_mfma_f32_16x16x32_bf16(kf0, qf[0], a, 0, 0, 0);
          a = __builtin_amdgcn_mfma_f32_16x16x32_bf16(kf1, qf[1], a, 0, 0, 0);
          st[kb] = a;
        } else {
          st[kb] = (f32x4){-1e30f, -1e30f, -1e30f, -1e30f};
        }
      }
      if (!full){
        const int keyb = t*64 + u*4;
        const int qr = q0 + l15;
#pragma unroll
        for (int kb = 0; kb < 4; kb++)
#pragma unroll
          for (int j = 0; j < 4; j++)
            st[kb][j] = (keyb + kb*16 + j > qr) ? -1e30f : st[kb][j];
      }

      // ---- online softmax (defer-max) ----
      {
        f32x4 mx = st[0];
#pragma unroll
        for (int kb = 1; kb < 4; kb++)
#pragma unroll
          for (int j = 0; j < 4; j++) mx[j] = fmaxf(mx[j], st[kb][j]);
        float tml = fmaxf(fmaxf(mx[0], mx[1]), fmaxf(mx[2], mx[3]));
        if (__any(tml > mrun + THR2)){
          float tm = fmaxf(tml, __shfl_xor(tml, 16));
          tm = fmaxf(tm, __shfl_xor(tm, 32));
          float mn = fmaxf(mrun, tm);
          float al = exp2f(mrun - mn);
          mrun = mn;
          lrun *= al;
#pragma unroll
          for (int d0 = 0; d0 < 4; d0++)
#pragma unroll
            for (int j = 0; j < 4; j++) o[d0][j] *= al;
        }
#pragma unroll
        for (int kb = 0; kb < 4; kb++)
#pragma unroll
          for (int j = 0; j < 4; j++){
            float p = exp2f(st[kb][j] - mrun);
            st[kb][j] = p;
            lrun += p;
          }
      }

      // ---- O^T += V^T-frag x P-frag; P packed in-lane (cvt_pk) ----
      __builtin_amdgcn_s_setprio(1);
#pragma unroll
      for (int kc = 0; kc < 2; kc++){
        union { uint32_t w[4]; bf16x8 v; } pb;
        asm("v_cvt_pk_bf16_f32 %0, %1, %2" : "=v"(pb.w[0]) : "v"(st[2*kc  ][0]), "v"(st[2*kc  ][1]));
        asm("v_cvt_pk_bf16_f32 %0, %1, %2" : "=v"(pb.w[1]) : "v"(st[2*kc  ][2]), "v"(st[2*kc  ][3]));
        asm("v_cvt_pk_bf16_f32 %0, %1, %2" : "=v"(pb.w[2]) : "v"(st[2*kc+1][0]), "v"(st[2*kc+1][1]));
        asm("v_cvt_pk_bf16_f32 %0, %1, %2" : "=v"(pb.w[3]) : "v"(st[2*kc+1][2]), "v"(st[2*kc+1][3]));
#pragma unroll
        for (int d0 = 0; d0 < 4; d0++){
          bf16x8 vb8 = *reinterpret_cast<const bf16x8*>(VB + voff[kc*4+d0]);
          o[d0] = __builtin_amdgcn_mfma_f32_16x16x32_bf16(vb8, pb.v, o[d0], 0, 0, 0);
        }
      }
      __builtin_amdgcn_s_setprio(0);

      __syncthreads();  // publishes tile t+1 + protects buffer reuse
    }
  }

  // epilogue: reduce lrun once; store NORMALIZED partial O + (m,l)
  {
    float lt = lrun + __shfl_xor(lrun, 16);
    lt += __shfl_xor(lt, 32);
    float inv = lt > 0.f ? 1.0f / lt : 0.f;
    const size_t ridx = (size_t)part*65536 + h*2048 + (q0 + l15);
#pragma unroll
    for (int d0 = 0; d0 < 4; d0++){
      ushort4 w;
      w.x = bf(o[d0][0] * inv); w.y = bf(o[d0][1] * inv);
      w.z = bf(o[d0][2] * inv); w.w = bf(o[d0][3] * inv);
      *reinterpret_cast<ushort4*>(&op[ridx*64 + d0*16 + u*4]) = w;
    }
    if (lane < 16) ml[ridx] = make_float2(mrun, lt);
  }
}

// ---------------- combine two KV-half partials -> ctx bf16 ----------------
// thread = (h, row, quarter of 16 dims). 1024 blocks x 256 threads.
__global__ __launch_bounds__(256) void k_comb(const ushort* __restrict__ op,
                                              const float2* __restrict__ ml,
                                              ushort* __restrict__ ctx){
  const int tq = blockIdx.x*256 + threadIdx.x;
  const int q = tq & 3, row = (tq >> 2) & 2047, h = tq >> 13;
  const int idx = h*2048 + row;
  float2 a = ml[idx], b = ml[idx + 65536];
  float m = fmaxf(a.x, b.x);
  float w0 = exp2f(a.x - m) * a.y;
  float w1 = exp2f(b.x - m) * b.y;
  float inv = 1.0f / (w0 + w1);
  w0 *= inv; w1 *= inv;
  const ushort4* p0 = reinterpret_cast<const ushort4*>(op + (size_t)idx*64 + q*16);
  const ushort4* p1 = reinterpret_cast<const ushort4*>(op + ((size_t)idx + 65536)*64 + q*16);
  ushort* dst = ctx + (size_t)row*2048 + h*64 + q*16;
#pragma unroll
  for (int i = 0; i < 4; i++){
    ushort4 x0 = p0[i], x1 = p1[i];
    ushort4 w;
    w.x = bf(w0*b2f(x0.x) + w1*b2f(x1.x));
    w.y = bf(w0*b2f(x0.y) + w1*b2f(x1.y));
    w.z = bf(w0*b2f(x0.z) + w1*b2f(x1.z));
    w.w = bf(w0*b2f(x0.w) + w1*b2f(x1.w));
    reinterpret_cast<ushort4*>(dst)[i] = w;
  }
}

// ---------------- launcher ----------------
extern "C" void kernel_launch(void* const* d_in, const int* in_sizes, int n_in,
                              void* d_out, int out_size, void* d_ws, size_t ws_size,
                              hipStream_t stream){
  const float* x    = (const float*)d_in[0];
  // d_in[1] = mask (unused; causal mask computed analytically)
  const float* cosp = (const float*)d_in[2];
  const float* sinp = (const float*)d_in[3];
  const float* wq   = (const float*)d_in[4];
  const float* wk   = (const float*)d_in[5];
  const float* wv   = (const float*)d_in[6];
  const float* wo   = (const float*)d_in[7];
  const float* qg   = (const float*)d_in[8];
  const float* kg   = (const float*)d_in[9];
  float* out = (float*)d_out;

  char* ws = (char*)d_ws;
  ushort* xb   = (ushort*)(ws);                    //  8 MB  x bf16
  ushort* wcat = (ushort*)(ws + 8388608);          // 12 MB  [wq;wk;wv] bf16
  ushort* wob  = (ushort*)(ws + 20971520);         //  8 MB  wo bf16
  ushort* qkvc = (ushort*)(ws + 29360128);         // 12 MB  qkv bf16 [2048][3072]
  ushort* qb   = (ushort*)(ws + 41943040);         //  8 MB  q bf16 (pre-scaled)
  ushort* kb   = (ushort*)(ws + 50331648);         //  2 MB  k bf16 [2048][512]
  ushort* vtb  = (ushort*)(ws + 52428800);         //  2 MB  v^T bf16 (slot-ordered)
  ushort* ctxb = (ushort*)(ws + 54525952);         //  8 MB  ctx bf16
  // partials OVERLAY xb+wcat (dead after k_gemm_btc):
  ushort* op   = (ushort*)(ws);                    // 16 MB  [2][32][2048][64] bf16
  float2* ml   = (float2*)(ws + 16777216);         //  1 MB  [2][32][2048] float2
  // total 62,914,560 bytes

  k_cvt_all<<<14336, 256, 0, stream>>>(x, wq, wk, wv, wo, xb, wcat, wob);
  k_gemm_btc<<<dim3(32, 16), 256, 0, stream>>>(xb, wcat, qkvc, 2048, 3072, 2048);
  k_normrope<<<2048, 256, 0, stream>>>(qkvc, cosp, sinp, qg, kg, qb, kb);
  k_vtrans<<<256, 256, 0, stream>>>(qkvc, vtb);
  k_attn<<<2048, 256, 0, stream>>>(qb, kb, vtb, op, ml);
  k_comb<<<1024, 256, 0, stream>>>(op, ml, ctxb);
  k_gemm_bt<<<dim3(32, 16), 256, 0, stream>>>(ctxb, wob, out, 2048, 2048, 2048);
}

// Round 14
// 135.615 us; speedup vs baseline: 1.1366x; 1.0233x over previous
//
#include <hip/hip_runtime.h>
#include <stdint.h>

// Problem constants (fixed-shape problem)
#define SEQ    2048
#define DMODEL 2048
#define NHEAD  32
#define NKV    8
#define HDIM   64
#define NQKV   3072   // 2048 q + 512 k + 512 v

typedef __bf16 bf16x8 __attribute__((ext_vector_type(8)));
typedef float  f32x4  __attribute__((ext_vector_type(4)));

#define SCALE2 0.180336880f   // 0.125 * log2(e): scores land in log2 domain
#define THR2   12.0f          // defer-max threshold (log2 domain); P <= 2^12

__device__ __forceinline__ ushort bf(float f){
  __bf16 h = (__bf16)f;               // native RNE convert on gfx950
  return __builtin_bit_cast(unsigned short, h);
}
__device__ __forceinline__ float b2f(ushort v){
  union { uint32_t u; float f; } a; a.u = ((uint32_t)v) << 16; return a.f;
}
__device__ __forceinline__ float ex2(float x){          // raw v_exp_f32
  return __builtin_amdgcn_exp2f(x);
}
__device__ __forceinline__ float fmax3(float a, float b, float c){
  float r;
  asm("v_max3_f32 %0, %1, %2, %3" : "=v"(r) : "v"(a), "v"(b), "v"(c));
  return r;
}

__device__ __forceinline__ void gl_lds16(const void* g, void* l){
  __builtin_amdgcn_global_load_lds(
      (const __attribute__((address_space(1))) uint32_t*)g,
      (__attribute__((address_space(3))) uint32_t*)l, 16, 0, 0);
}

// ------------- all f32->bf16 converts in one kernel -------------
__global__ __launch_bounds__(256) void k_cvt_all(const float* __restrict__ x,
                                                 const float* __restrict__ wq,
                                                 const float* __restrict__ wk,
                                                 const float* __restrict__ wv,
                                                 const float* __restrict__ wo,
                                                 ushort* __restrict__ xb,
                                                 ushort* __restrict__ wcat,
                                                 ushort* __restrict__ wob){
  int i = blockIdx.x * 256 + threadIdx.x;
  const float* src; ushort* dst; int s4; int d4;
  if (i < 1048576)      { src = x;  dst = xb;   s4 = i;           d4 = s4; }
  else if (i < 2097152) { src = wq; dst = wcat; s4 = i - 1048576; d4 = s4; }
  else if (i < 2359296) { src = wk; dst = wcat; s4 = i - 2097152; d4 = s4 + 1048576; }
  else if (i < 2621440) { src = wv; dst = wcat; s4 = i - 2359296; d4 = s4 + 1310720; }
  else                  { src = wo; dst = wob;  s4 = i - 2621440; d4 = s4; }
  float4 v = reinterpret_cast<const float4*>(src)[s4];
  ushort4 o;
  o.x = bf(v.x); o.y = bf(v.y); o.z = bf(v.z); o.w = bf(v.w);
  reinterpret_cast<ushort4*>(dst)[d4] = o;
}

// ---------------- GEMM (f32 out): C = A[M][K] x B[N][K]^T ----------------
// Tile 128x64, BK=64, 4 waves (2x2; per-wave 64x32). Grid (N/64, M/128) =
// 512 blocks = exactly 2/CU, LDS 49KB -> both resident, 8 waves/CU.
__global__ __launch_bounds__(256) void k_gemm_bt(const ushort* __restrict__ A,
                                                 const ushort* __restrict__ B,
                                                 float* __restrict__ C,
                                                 int M, int N, int K){
  __shared__ ushort As[2][128*64];
  __shared__ ushort Bs[2][64*64];
  const int tid = threadIdx.x, lane = tid & 63, wid = tid >> 6;
  const int bm = blockIdx.y * 128, bn = blockIdx.x * 64;
  const int wr = wid >> 1, wc = wid & 1;
  const int l15 = lane & 15, u = lane >> 4;

  const int crow = lane >> 3;                       // row within 8-row chunk
  const int scol = ((lane & 7) ^ crow) * 8;         // pre-swizzled 16B slot
  const ushort* Abase = A + (size_t)(bm + wid*32 + crow) * K + scol;
  const ushort* Bbase = B + (size_t)(bn + wid*16 + crow) * K + scol;

  auto STAGE = [&](int buf, int k0){
#pragma unroll
    for (int c = 0; c < 4; c++)
      gl_lds16(Abase + k0 + (size_t)c*8*K, &As[buf][(wid*32 + c*8)*64]);
#pragma unroll
    for (int c = 0; c < 2; c++)
      gl_lds16(Bbase + k0 + (size_t)c*8*K, &Bs[buf][(wid*16 + c*8)*64]);
  };

  f32x4 acc[4][2] = {};
  const int NT = K >> 6;

  STAGE(0, 0);
  __syncthreads();

  for (int t = 0; t < NT; t++){
    const int cur = t & 1;
    if (t + 1 < NT) STAGE(cur ^ 1, (t + 1) << 6);

#pragma unroll
    for (int kc = 0; kc < 2; kc++){
      bf16x8 af[4], bfr[2];
#pragma unroll
      for (int m = 0; m < 4; m++){
        int row = wr*64 + m*16 + l15;
        af[m] = *reinterpret_cast<const bf16x8*>(&As[cur][row*64 + (((kc*4+u) ^ (row&7))*8)]);
      }
#pragma unroll
      for (int n = 0; n < 2; n++){
        int row = wc*32 + n*16 + l15;
        bfr[n] = *reinterpret_cast<const bf16x8*>(&Bs[cur][row*64 + (((kc*4+u) ^ (row&7))*8)]);
      }
      __builtin_amdgcn_s_setprio(1);
#pragma unroll
      for (int m = 0; m < 4; m++)
#pragma unroll
        for (int n = 0; n < 2; n++)
          acc[m][n] = __builtin_amdgcn_mfma_f32_16x16x32_bf16(af[m], bfr[n], acc[m][n], 0, 0, 0);
      __builtin_amdgcn_s_setprio(0);
    }

    __syncthreads();
  }

#pragma unroll
  for (int m = 0; m < 4; m++)
#pragma unroll
    for (int n = 0; n < 2; n++)
#pragma unroll
      for (int j = 0; j < 4; j++){
        int row = bm + wr*64 + m*16 + u*4 + j;
        int col = bn + wc*32 + n*16 + l15;
        C[(size_t)row * N + col] = acc[m][n][j];
      }
}

// ---------------- GEMM (bf16 out): qkvc = xb x wcat^T ----------------
// Tile 128x96, BK=64, 4 waves (2x2; per-wave 64x48). Grid (32,16) = 512
// blocks = exactly 2/CU, LDS 57KB -> both resident.
__global__ __launch_bounds__(256) void k_gemm_btc(const ushort* __restrict__ A,
                                                  const ushort* __restrict__ B,
                                                  ushort* __restrict__ C,
                                                  int M, int N, int K){
  __shared__ ushort As[2][128*64];
  __shared__ ushort Bs[2][96*64];
  const int tid = threadIdx.x, lane = tid & 63, wid = tid >> 6;
  const int bm = blockIdx.y * 128, bn = blockIdx.x * 96;
  const int wr = wid >> 1, wc = wid & 1;
  const int l15 = lane & 15, u = lane >> 4;

  const int crow = lane >> 3;
  const int scol = ((lane & 7) ^ crow) * 8;
  const ushort* Abase = A + (size_t)(bm + wid*32 + crow) * K + scol;
  const ushort* Bbase = B + (size_t)(bn + wid*24 + crow) * K + scol;

  auto STAGE = [&](int buf, int k0){
#pragma unroll
    for (int c = 0; c < 4; c++)
      gl_lds16(Abase + k0 + (size_t)c*8*K, &As[buf][(wid*32 + c*8)*64]);
#pragma unroll
    for (int c = 0; c < 3; c++)
      gl_lds16(Bbase + k0 + (size_t)c*8*K, &Bs[buf][(wid*24 + c*8)*64]);
  };

  f32x4 acc[4][3] = {};
  const int NT = K >> 6;

  STAGE(0, 0);
  __syncthreads();

  for (int t = 0; t < NT; t++){
    const int cur = t & 1;
    if (t + 1 < NT) STAGE(cur ^ 1, (t + 1) << 6);

#pragma unroll
    for (int kc = 0; kc < 2; kc++){
      bf16x8 af[4], bfr[3];
#pragma unroll
      for (int m = 0; m < 4; m++){
        int row = wr*64 + m*16 + l15;
        af[m] = *reinterpret_cast<const bf16x8*>(&As[cur][row*64 + (((kc*4+u) ^ (row&7))*8)]);
      }
#pragma unroll
      for (int n = 0; n < 3; n++){
        int row = wc*48 + n*16 + l15;
        bfr[n] = *reinterpret_cast<const bf16x8*>(&Bs[cur][row*64 + (((kc*4+u) ^ (row&7))*8)]);
      }
      __builtin_amdgcn_s_setprio(1);
#pragma unroll
      for (int m = 0; m < 4; m++)
#pragma unroll
        for (int n = 0; n < 3; n++)
          acc[m][n] = __builtin_amdgcn_mfma_f32_16x16x32_bf16(af[m], bfr[n], acc[m][n], 0, 0, 0);
      __builtin_amdgcn_s_setprio(0);
    }

    __syncthreads();
  }

#pragma unroll
  for (int m = 0; m < 4; m++)
#pragma unroll
    for (int n = 0; n < 3; n++)
#pragma unroll
      for (int j = 0; j < 4; j++){
        int row = bm + wr*64 + m*16 + u*4 + j;
        int col = bn + wc*48 + n*16 + l15;
        C[(size_t)row * N + col] = bf(acc[m][n][j]);
      }
}

// ---------------- fused RMSNorm + RoPE (bf16 in, bf16 out; q, k only) -------
__global__ __launch_bounds__(256) void k_normrope(const ushort* __restrict__ qkvc,
                                                  const float* __restrict__ cosp,
                                                  const float* __restrict__ sinp,
                                                  const float* __restrict__ qg,
                                                  const float* __restrict__ kg,
                                                  ushort* __restrict__ qb,
                                                  ushort* __restrict__ kb){
  const int s = blockIdx.x;
  const int tid = threadIdx.x, lane = tid & 63, wid = tid >> 6;
  const ushort* row = qkvc + (size_t)s * NQKV;
  const float cs = cosp[s*HDIM + lane];
  const float sn = sinp[s*HDIM + lane];

  for (int hidx = wid; hidx < 40; hidx += 4){
    const bool isq = hidx < 32;
    const int col = isq ? hidx*64 : 2048 + (hidx-32)*64;
    float x = b2f(row[col + lane]);
    float ss = x * x;
#pragma unroll
    for (int m = 1; m < 64; m <<= 1) ss += __shfl_xor(ss, m);
    float r = rsqrtf(ss * (1.0f/64.0f) + 1e-6f);
    float y = x * r * (isq ? qg : kg)[lane];
    float p = __shfl_xor(y, 32);
    float out = y * cs + (lane < 32 ? -p : p) * sn;
    if (isq) qb[(size_t)s*2048 + hidx*64 + lane] = bf(out * SCALE2);
    else     kb[(size_t)s*512 + (hidx-32)*64 + lane] = bf(out);
  }
}

// ---------------- V transpose: qkvc v-section bf16 -> vtb (slot-ordered) ----
__global__ __launch_bounds__(256) void k_vtrans(const ushort* __restrict__ qkvc,
                                                ushort* __restrict__ vtb){
  __shared__ ushort tile[64][68];     // [d][s], pad 68
  const int g = blockIdx.x >> 5, st = blockIdx.x & 31;
  const int tid = threadIdx.x;
#pragma unroll
  for (int i = 0; i < 4; i++){
    int idx = i*256 + tid;
    int r = idx >> 4, c4 = idx & 15;
    ushort4 v = *reinterpret_cast<const ushort4*>(
        qkvc + (size_t)(st*64 + r)*NQKV + 2560 + g*64 + c4*4);
    tile[c4*4+0][r] = v.x;
    tile[c4*4+1][r] = v.y;
    tile[c4*4+2][r] = v.z;
    tile[c4*4+3][r] = v.w;
  }
  __syncthreads();
#pragma unroll
  for (int i = 0; i < 4; i++){
    int idx = i*256 + tid;
    int d = idx >> 4, s4 = idx & 15;
    // sigma: key chunk s4=(kb,u) -> PV-slot-ordered position
    int pos4 = (s4 >> 3)*32 + (s4 & 3)*8 + ((s4 >> 2) & 1)*4;
    ushort4 o = *reinterpret_cast<const ushort4*>(&tile[d][s4*4]);
    *reinterpret_cast<ushort4*>(vtb + (size_t)(g*64 + d)*SEQ + st*64 + pos4) = o;
  }
}

// ---------------- causal flash GQA attention, SPLIT-KV (2 parts) ----------
// Block = (head, 64-row q-tile, KV-half). Grid 2048 (qt descending = LPT):
// 5 resident/CU + backfill. Writes normalized partial O + (m,l); k_comb merges.
__global__ __launch_bounds__(256) void k_attn(const ushort* __restrict__ qbuf,
                                              const ushort* __restrict__ kbuf,
                                              const ushort* __restrict__ vtb,
                                              ushort* __restrict__ op,
                                              float2* __restrict__ ml){
  __shared__ ushort Kd[2][64*64];       // swizzled K tiles   (16 KB)
  __shared__ ushort Vd[2][64*64];       // swizzled V^T tiles (16 KB)

  const int bx = blockIdx.x;
  const int qt   = 31 - (bx >> 6);      // descending: longest parts first
  const int part = (bx >> 5) & 1;
  const int h    = bx & 31;
  const int g = h >> 2;
  const int n  = qt + 1;
  const int h1 = (n + 1) >> 1;
  const int t0 = part ? h1 : 0;
  const int t1 = part ? n  : h1;
  const int tid = threadIdx.x, lane = tid & 63, wid = tid >> 6;
  const int l15 = lane & 15, u = lane >> 4;
  const int q0 = qt*64 + wid*16;        // wave's first q-row

  // Q fragments (B-operand: col=l15 -> q-row)
  bf16x8 qf[2];
#pragma unroll
  for (int kc = 0; kc < 2; kc++)
    qf[kc] = *reinterpret_cast<const bf16x8*>(
        qbuf + (size_t)(q0 + l15)*2048 + h*64 + kc*32 + u*8);

  f32x4 o[4] = {};                      // O^T: o[d0][j] = O[q=l15][d0*16+u*4+j]
  float mrun = -1e30f;
  float lrun = 0.f;                     // per-lane partial (reduced at end)

  // hoisted swizzled LDS byte-offsets (loop-invariant, static-indexed)
  int koff[8], voff[8];
#pragma unroll
  for (int kb = 0; kb < 4; kb++)
#pragma unroll
    for (int kc = 0; kc < 2; kc++){
      int keyl = kb*16 + l15;
      koff[kb*2+kc] = (keyl*64 + (((kc*4+u) ^ (keyl&7))*8)) * 2;
    }
#pragma unroll
  for (int kc = 0; kc < 2; kc++)
#pragma unroll
    for (int d0 = 0; d0 < 4; d0++){
      int vrow = d0*16 + l15;
      voff[kc*4+d0] = (vrow*64 + (((kc*4+u) ^ (vrow&7))*8)) * 2;
    }

  // staging: 8 chunks of 1KB per tile; wave does 2 K + 2 V
  const int srow = wid*16 + (lane >> 3);
  const int scol = ((lane & 7) ^ (lane >> 3)) * 8;
  const ushort* ksrc0 = kbuf + (size_t)srow*512 + g*64 + scol;
  const ushort* vsrc0 = vtb  + (size_t)(g*64 + srow)*SEQ + scol;

  auto STAGE = [&](int buf, int t){
    const ushort* ks = ksrc0 + (size_t)t*64*512;
    gl_lds16(ks,         &Kd[buf][wid*1024]);
    gl_lds16(ks + 8*512, &Kd[buf][wid*1024 + 512]);
    const ushort* vs = vsrc0 + t*64;
    gl_lds16(vs,          &Vd[buf][wid*1024]);
    gl_lds16(vs + 8*SEQ,  &Vd[buf][wid*1024 + 512]);
  };

  if (t0 < t1){
    STAGE(0, t0);
    __syncthreads();   // drains vmcnt(0): first tile visible

    for (int t = t0; t < t1; t++){
      const int cur = (t - t0) & 1;
      if (t + 1 < t1) STAGE(cur ^ 1, t + 1);

      const char* KB = (const char*)Kd + cur*8192;
      const char* VB = (const char*)Vd + cur*8192;
      const bool full = (t*64 + 63) <= q0;

      // ---- S^T = mfma(K, Q) ----
      f32x4 st[4];
#pragma unroll
      for (int kb = 0; kb < 4; kb++){
        const int key0 = t*64 + kb*16;
        if (key0 <= q0 + 15){
          bf16x8 kf0 = *reinterpret_cast<const bf16x8*>(KB + koff[kb*2]);
          bf16x8 kf1 = *reinterpret_cast<const bf16x8*>(KB + koff[kb*2+1]);
          f32x4 a = {};
          a = __builtin_amdgcn_mfma_f32_16x16x32_bf16(kf0, qf[0], a, 0, 0, 0);
          a = __builtin_amdgcn_mfma_f32_16x16x32_bf16(kf1, qf[1], a, 0, 0, 0);
          st[kb] = a;
        } else {
          st[kb] = (f32x4){-1e30f, -1e30f, -1e30f, -1e30f};
        }
      }
      if (!full){
        const int keyb = t*64 + u*4;
        const int qr = q0 + l15;
#pragma unroll
        for (int kb = 0; kb < 4; kb++)
#pragma unroll
          for (int j = 0; j < 4; j++)
            st[kb][j] = (keyb + kb*16 + j > qr) ? -1e30f : st[kb][j];
      }

      // ---- online softmax (defer-max; raw v_exp + max3 tree) ----
      {
        // 16-value max in 8 v_max3 + 1 v_max (vs 15-deep serial fmax chain)
        float r0 = fmax3(st[0][0], st[0][1], st[0][2]);
        float r1 = fmax3(st[0][3], st[1][0], st[1][1]);
        float r2 = fmax3(st[1][2], st[1][3], st[2][0]);
        float r3 = fmax3(st[2][1], st[2][2], st[2][3]);
        float r4 = fmax3(st[3][0], st[3][1], st[3][2]);
        float m0 = fmax3(r0, r1, r2);
        float m1 = fmax3(r3, r4, st[3][3]);
        float tml = fmaxf(m0, m1);
        if (__any(tml > mrun + THR2)){
          float tm = fmaxf(tml, __shfl_xor(tml, 16));
          tm = fmaxf(tm, __shfl_xor(tm, 32));
          float mn = fmaxf(mrun, tm);
          float al = ex2(mrun - mn);
          mrun = mn;
          lrun *= al;
#pragma unroll
          for (int d0 = 0; d0 < 4; d0++)
#pragma unroll
            for (int j = 0; j < 4; j++) o[d0][j] *= al;
        }
        // exp via raw v_exp_f32 (single inst); tree-reassociated row sum
        float ls[4];
#pragma unroll
        for (int kb = 0; kb < 4; kb++){
          float p0 = ex2(st[kb][0] - mrun);
          float p1 = ex2(st[kb][1] - mrun);
          float p2 = ex2(st[kb][2] - mrun);
          float p3 = ex2(st[kb][3] - mrun);
          st[kb][0] = p0; st[kb][1] = p1; st[kb][2] = p2; st[kb][3] = p3;
          ls[kb] = (p0 + p1) + (p2 + p3);
        }
        lrun += (ls[0] + ls[1]) + (ls[2] + ls[3]);
      }

      // ---- O^T += V^T-frag x P-frag; P packed in-lane (cvt_pk) ----
      __builtin_amdgcn_s_setprio(1);
#pragma unroll
      for (int kc = 0; kc < 2; kc++){
        union { uint32_t w[4]; bf16x8 v; } pb;
        asm("v_cvt_pk_bf16_f32 %0, %1, %2" : "=v"(pb.w[0]) : "v"(st[2*kc  ][0]), "v"(st[2*kc  ][1]));
        asm("v_cvt_pk_bf16_f32 %0, %1, %2" : "=v"(pb.w[1]) : "v"(st[2*kc  ][2]), "v"(st[2*kc  ][3]));
        asm("v_cvt_pk_bf16_f32 %0, %1, %2" : "=v"(pb.w[2]) : "v"(st[2*kc+1][0]), "v"(st[2*kc+1][1]));
        asm("v_cvt_pk_bf16_f32 %0, %1, %2" : "=v"(pb.w[3]) : "v"(st[2*kc+1][2]), "v"(st[2*kc+1][3]));
#pragma unroll
        for (int d0 = 0; d0 < 4; d0++){
          bf16x8 vb8 = *reinterpret_cast<const bf16x8*>(VB + voff[kc*4+d0]);
          o[d0] = __builtin_amdgcn_mfma_f32_16x16x32_bf16(vb8, pb.v, o[d0], 0, 0, 0);
        }
      }
      __builtin_amdgcn_s_setprio(0);

      __syncthreads();  // publishes tile t+1 + protects buffer reuse
    }
  }

  // epilogue: reduce lrun once; store NORMALIZED partial O + (m,l)
  {
    float lt = lrun + __shfl_xor(lrun, 16);
    lt += __shfl_xor(lt, 32);
    float inv = lt > 0.f ? 1.0f / lt : 0.f;
    const size_t ridx = (size_t)part*65536 + h*2048 + (q0 + l15);
#pragma unroll
    for (int d0 = 0; d0 < 4; d0++){
      ushort4 w;
      w.x = bf(o[d0][0] * inv); w.y = bf(o[d0][1] * inv);
      w.z = bf(o[d0][2] * inv); w.w = bf(o[d0][3] * inv);
      *reinterpret_cast<ushort4*>(&op[ridx*64 + d0*16 + u*4]) = w;
    }
    if (lane < 16) ml[ridx] = make_float2(mrun, lt);
  }
}

// ---------------- combine two KV-half partials -> ctx bf16 ----------------
__global__ __launch_bounds__(256) void k_comb(const ushort* __restrict__ op,
                                              const float2* __restrict__ ml,
                                              ushort* __restrict__ ctx){
  const int tq = blockIdx.x*256 + threadIdx.x;
  const int q = tq & 3, row = (tq >> 2) & 2047, h = tq >> 13;
  const int idx = h*2048 + row;
  float2 a = ml[idx], b = ml[idx + 65536];
  float m = fmaxf(a.x, b.x);
  float w0 = ex2(a.x - m) * a.y;
  float w1 = ex2(b.x - m) * b.y;
  float inv = 1.0f / (w0 + w1);
  w0 *= inv; w1 *= inv;
  const ushort4* p0 = reinterpret_cast<const ushort4*>(op + (size_t)idx*64 + q*16);
  const ushort4* p1 = reinterpret_cast<const ushort4*>(op + ((size_t)idx + 65536)*64 + q*16);
  ushort* dst = ctx + (size_t)row*2048 + h*64 + q*16;
#pragma unroll
  for (int i = 0; i < 4; i++){
    ushort4 x0 = p0[i], x1 = p1[i];
    ushort4 w;
    w.x = bf(w0*b2f(x0.x) + w1*b2f(x1.x));
    w.y = bf(w0*b2f(x0.y) + w1*b2f(x1.y));
    w.z = bf(w0*b2f(x0.z) + w1*b2f(x1.z));
    w.w = bf(w0*b2f(x0.w) + w1*b2f(x1.w));
    reinterpret_cast<ushort4*>(dst)[i] = w;
  }
}

// ---------------- launcher ----------------
extern "C" void kernel_launch(void* const* d_in, const int* in_sizes, int n_in,
                              void* d_out, int out_size, void* d_ws, size_t ws_size,
                              hipStream_t stream){
  const float* x    = (const float*)d_in[0];
  // d_in[1] = mask (unused; causal mask computed analytically)
  const float* cosp = (const float*)d_in[2];
  const float* sinp = (const float*)d_in[3];
  const float* wq   = (const float*)d_in[4];
  const float* wk   = (const float*)d_in[5];
  const float* wv   = (const float*)d_in[6];
  const float* wo   = (const float*)d_in[7];
  const float* qg   = (const float*)d_in[8];
  const float* kg   = (const float*)d_in[9];
  float* out = (float*)d_out;

  char* ws = (char*)d_ws;
  ushort* xb   = (ushort*)(ws);                    //  8 MB  x bf16
  ushort* wcat = (ushort*)(ws + 8388608);          // 12 MB  [wq;wk;wv] bf16
  ushort* wob  = (ushort*)(ws + 20971520);         //  8 MB  wo bf16
  ushort* qkvc = (ushort*)(ws + 29360128);         // 12 MB  qkv bf16 [2048][3072]
  ushort* qb   = (ushort*)(ws + 41943040);         //  8 MB  q bf16 (pre-scaled)
  ushort* kb   = (ushort*)(ws + 50331648);         //  2 MB  k bf16 [2048][512]
  ushort* vtb  = (ushort*)(ws + 52428800);         //  2 MB  v^T bf16 (slot-ordered)
  ushort* ctxb = (ushort*)(ws + 54525952);         //  8 MB  ctx bf16
  // partials OVERLAY xb+wcat (dead after k_gemm_btc):
  ushort* op   = (ushort*)(ws);                    // 16 MB  [2][32][2048][64] bf16
  float2* ml   = (float2*)(ws + 16777216);         //  1 MB  [2][32][2048] float2
  // total 62,914,560 bytes

  k_cvt_all<<<14336, 256, 0, stream>>>(x, wq, wk, wv, wo, xb, wcat, wob);
  k_gemm_btc<<<dim3(32, 16), 256, 0, stream>>>(xb, wcat, qkvc, 2048, 3072, 2048);
  k_normrope<<<2048, 256, 0, stream>>>(qkvc, cosp, sinp, qg, kg, qb, kb);
  k_vtrans<<<256, 256, 0, stream>>>(qkvc, vtb);
  k_attn<<<2048, 256, 0, stream>>>(qb, kb, vtb, op, ml);
  k_comb<<<1024, 256, 0, stream>>>(op, ml, ctxb);
  k_gemm_bt<<<dim3(32, 16), 256, 0, stream>>>(ctxb, wob, out, 2048, 2048, 2048);
}

// Round 15
// 130.578 us; speedup vs baseline: 1.1805x; 1.0386x over previous
//
#include <hip/hip_runtime.h>
#include <stdint.h>

// Problem constants (fixed-shape problem)
#define SEQ    2048
#define DMODEL 2048
#define NHEAD  32
#define NKV    8
#define HDIM   64
#define NQKV   3072   // 2048 q + 512 k + 512 v

typedef __bf16 bf16x8 __attribute__((ext_vector_type(8)));
typedef float  f32x4  __attribute__((ext_vector_type(4)));

#define SCALE2 0.180336880f   // 0.125 * log2(e): scores land in log2 domain
#define THR2   12.0f          // defer-max threshold (log2 domain); P <= 2^12

__device__ __forceinline__ ushort bf(float f){
  __bf16 h = (__bf16)f;               // native RNE convert on gfx950
  return __builtin_bit_cast(unsigned short, h);
}
__device__ __forceinline__ float b2f(ushort v){
  union { uint32_t u; float f; } a; a.u = ((uint32_t)v) << 16; return a.f;
}
__device__ __forceinline__ float ex2(float x){          // raw v_exp_f32
  return __builtin_amdgcn_exp2f(x);
}
__device__ __forceinline__ float fmax3(float a, float b, float c){
  float r;
  asm("v_max3_f32 %0, %1, %2, %3" : "=v"(r) : "v"(a), "v"(b), "v"(c));
  return r;
}

__device__ __forceinline__ void gl_lds16(const void* g, void* l){
  __builtin_amdgcn_global_load_lds(
      (const __attribute__((address_space(1))) uint32_t*)g,
      (__attribute__((address_space(3))) uint32_t*)l, 16, 0, 0);
}

// ------------- all f32->bf16 converts in one kernel -------------
__global__ __launch_bounds__(256) void k_cvt_all(const float* __restrict__ x,
                                                 const float* __restrict__ wq,
                                                 const float* __restrict__ wk,
                                                 const float* __restrict__ wv,
                                                 const float* __restrict__ wo,
                                                 ushort* __restrict__ xb,
                                                 ushort* __restrict__ wcat,
                                                 ushort* __restrict__ wob){
  int i = blockIdx.x * 256 + threadIdx.x;
  const float* src; ushort* dst; int s4; int d4;
  if (i < 1048576)      { src = x;  dst = xb;   s4 = i;           d4 = s4; }
  else if (i < 2097152) { src = wq; dst = wcat; s4 = i - 1048576; d4 = s4; }
  else if (i < 2359296) { src = wk; dst = wcat; s4 = i - 2097152; d4 = s4 + 1048576; }
  else if (i < 2621440) { src = wv; dst = wcat; s4 = i - 2359296; d4 = s4 + 1310720; }
  else                  { src = wo; dst = wob;  s4 = i - 2621440; d4 = s4; }
  float4 v = reinterpret_cast<const float4*>(src)[s4];
  ushort4 o;
  o.x = bf(v.x); o.y = bf(v.y); o.z = bf(v.z); o.w = bf(v.w);
  reinterpret_cast<ushort4*>(dst)[d4] = o;
}

// ---------------- GEMM (f32 out): C = A[M][K] x B[N][K]^T ----------------
// Tile 128x64, BK=64, 4 waves (2x2; per-wave 64x32). Grid (N/64, M/128) =
// 512 blocks = exactly 2/CU, LDS 49KB -> both resident, 8 waves/CU.
__global__ __launch_bounds__(256) void k_gemm_bt(const ushort* __restrict__ A,
                                                 const ushort* __restrict__ B,
                                                 float* __restrict__ C,
                                                 int M, int N, int K){
  __shared__ ushort As[2][128*64];
  __shared__ ushort Bs[2][64*64];
  const int tid = threadIdx.x, lane = tid & 63, wid = tid >> 6;
  const int bm = blockIdx.y * 128, bn = blockIdx.x * 64;
  const int wr = wid >> 1, wc = wid & 1;
  const int l15 = lane & 15, u = lane >> 4;

  const int crow = lane >> 3;                       // row within 8-row chunk
  const int scol = ((lane & 7) ^ crow) * 8;         // pre-swizzled 16B slot
  const ushort* Abase = A + (size_t)(bm + wid*32 + crow) * K + scol;
  const ushort* Bbase = B + (size_t)(bn + wid*16 + crow) * K + scol;

  auto STAGE = [&](int buf, int k0){
#pragma unroll
    for (int c = 0; c < 4; c++)
      gl_lds16(Abase + k0 + (size_t)c*8*K, &As[buf][(wid*32 + c*8)*64]);
#pragma unroll
    for (int c = 0; c < 2; c++)
      gl_lds16(Bbase + k0 + (size_t)c*8*K, &Bs[buf][(wid*16 + c*8)*64]);
  };

  f32x4 acc[4][2] = {};
  const int NT = K >> 6;

  STAGE(0, 0);
  __syncthreads();

  for (int t = 0; t < NT; t++){
    const int cur = t & 1;
    if (t + 1 < NT) STAGE(cur ^ 1, (t + 1) << 6);

#pragma unroll
    for (int kc = 0; kc < 2; kc++){
      bf16x8 af[4], bfr[2];
#pragma unroll
      for (int m = 0; m < 4; m++){
        int row = wr*64 + m*16 + l15;
        af[m] = *reinterpret_cast<const bf16x8*>(&As[cur][row*64 + (((kc*4+u) ^ (row&7))*8)]);
      }
#pragma unroll
      for (int n = 0; n < 2; n++){
        int row = wc*32 + n*16 + l15;
        bfr[n] = *reinterpret_cast<const bf16x8*>(&Bs[cur][row*64 + (((kc*4+u) ^ (row&7))*8)]);
      }
      __builtin_amdgcn_s_setprio(1);
#pragma unroll
      for (int m = 0; m < 4; m++)
#pragma unroll
        for (int n = 0; n < 2; n++)
          acc[m][n] = __builtin_amdgcn_mfma_f32_16x16x32_bf16(af[m], bfr[n], acc[m][n], 0, 0, 0);
      __builtin_amdgcn_s_setprio(0);
    }

    __syncthreads();
  }

#pragma unroll
  for (int m = 0; m < 4; m++)
#pragma unroll
    for (int n = 0; n < 2; n++)
#pragma unroll
      for (int j = 0; j < 4; j++){
        int row = bm + wr*64 + m*16 + u*4 + j;
        int col = bn + wc*32 + n*16 + l15;
        C[(size_t)row * N + col] = acc[m][n][j];
      }
}

// ---------------- GEMM (bf16 out): qkvc = xb x wcat^T ----------------
// Tile 128x96, BK=64, 4 waves (2x2; per-wave 64x48). Grid (32,16) = 512
// blocks = exactly 2/CU, LDS 57KB -> both resident.
__global__ __launch_bounds__(256) void k_gemm_btc(const ushort* __restrict__ A,
                                                  const ushort* __restrict__ B,
                                                  ushort* __restrict__ C,
                                                  int M, int N, int K){
  __shared__ ushort As[2][128*64];
  __shared__ ushort Bs[2][96*64];
  const int tid = threadIdx.x, lane = tid & 63, wid = tid >> 6;
  const int bm = blockIdx.y * 128, bn = blockIdx.x * 96;
  const int wr = wid >> 1, wc = wid & 1;
  const int l15 = lane & 15, u = lane >> 4;

  const int crow = lane >> 3;
  const int scol = ((lane & 7) ^ crow) * 8;
  const ushort* Abase = A + (size_t)(bm + wid*32 + crow) * K + scol;
  const ushort* Bbase = B + (size_t)(bn + wid*24 + crow) * K + scol;

  auto STAGE = [&](int buf, int k0){
#pragma unroll
    for (int c = 0; c < 4; c++)
      gl_lds16(Abase + k0 + (size_t)c*8*K, &As[buf][(wid*32 + c*8)*64]);
#pragma unroll
    for (int c = 0; c < 3; c++)
      gl_lds16(Bbase + k0 + (size_t)c*8*K, &Bs[buf][(wid*24 + c*8)*64]);
  };

  f32x4 acc[4][3] = {};
  const int NT = K >> 6;

  STAGE(0, 0);
  __syncthreads();

  for (int t = 0; t < NT; t++){
    const int cur = t & 1;
    if (t + 1 < NT) STAGE(cur ^ 1, (t + 1) << 6);

#pragma unroll
    for (int kc = 0; kc < 2; kc++){
      bf16x8 af[4], bfr[3];
#pragma unroll
      for (int m = 0; m < 4; m++){
        int row = wr*64 + m*16 + l15;
        af[m] = *reinterpret_cast<const bf16x8*>(&As[cur][row*64 + (((kc*4+u) ^ (row&7))*8)]);
      }
#pragma unroll
      for (int n = 0; n < 3; n++){
        int row = wc*48 + n*16 + l15;
        bfr[n] = *reinterpret_cast<const bf16x8*>(&Bs[cur][row*64 + (((kc*4+u) ^ (row&7))*8)]);
      }
      __builtin_amdgcn_s_setprio(1);
#pragma unroll
      for (int m = 0; m < 4; m++)
#pragma unroll
        for (int n = 0; n < 3; n++)
          acc[m][n] = __builtin_amdgcn_mfma_f32_16x16x32_bf16(af[m], bfr[n], acc[m][n], 0, 0, 0);
      __builtin_amdgcn_s_setprio(0);
    }

    __syncthreads();
  }

#pragma unroll
  for (int m = 0; m < 4; m++)
#pragma unroll
    for (int n = 0; n < 3; n++)
#pragma unroll
      for (int j = 0; j < 4; j++){
        int row = bm + wr*64 + m*16 + u*4 + j;
        int col = bn + wc*48 + n*16 + l15;
        C[(size_t)row * N + col] = bf(acc[m][n][j]);
      }
}

// ---------------- fused RMSNorm + RoPE (bf16 in, bf16 out; q, k only) -------
__global__ __launch_bounds__(256) void k_normrope(const ushort* __restrict__ qkvc,
                                                  const float* __restrict__ cosp,
                                                  const float* __restrict__ sinp,
                                                  const float* __restrict__ qg,
                                                  const float* __restrict__ kg,
                                                  ushort* __restrict__ qb,
                                                  ushort* __restrict__ kb){
  const int s = blockIdx.x;
  const int tid = threadIdx.x, lane = tid & 63, wid = tid >> 6;
  const ushort* row = qkvc + (size_t)s * NQKV;
  const float cs = cosp[s*HDIM + lane];
  const float sn = sinp[s*HDIM + lane];

  for (int hidx = wid; hidx < 40; hidx += 4){
    const bool isq = hidx < 32;
    const int col = isq ? hidx*64 : 2048 + (hidx-32)*64;
    float x = b2f(row[col + lane]);
    float ss = x * x;
#pragma unroll
    for (int m = 1; m < 64; m <<= 1) ss += __shfl_xor(ss, m);
    float r = rsqrtf(ss * (1.0f/64.0f) + 1e-6f);
    float y = x * r * (isq ? qg : kg)[lane];
    float p = __shfl_xor(y, 32);
    float out = y * cs + (lane < 32 ? -p : p) * sn;
    if (isq) qb[(size_t)s*2048 + hidx*64 + lane] = bf(out * SCALE2);
    else     kb[(size_t)s*512 + (hidx-32)*64 + lane] = bf(out);
  }
}

// ---------------- V transpose: qkvc v-section bf16 -> vtb (slot-ordered) ----
__global__ __launch_bounds__(256) void k_vtrans(const ushort* __restrict__ qkvc,
                                                ushort* __restrict__ vtb){
  __shared__ ushort tile[64][68];     // [d][s], pad 68
  const int g = blockIdx.x >> 5, st = blockIdx.x & 31;
  const int tid = threadIdx.x;
#pragma unroll
  for (int i = 0; i < 4; i++){
    int idx = i*256 + tid;
    int r = idx >> 4, c4 = idx & 15;
    ushort4 v = *reinterpret_cast<const ushort4*>(
        qkvc + (size_t)(st*64 + r)*NQKV + 2560 + g*64 + c4*4);
    tile[c4*4+0][r] = v.x;
    tile[c4*4+1][r] = v.y;
    tile[c4*4+2][r] = v.z;
    tile[c4*4+3][r] = v.w;
  }
  __syncthreads();
#pragma unroll
  for (int i = 0; i < 4; i++){
    int idx = i*256 + tid;
    int d = idx >> 4, s4 = idx & 15;
    // sigma: key chunk s4=(kb,u) -> PV-slot-ordered position
    int pos4 = (s4 >> 3)*32 + (s4 & 3)*8 + ((s4 >> 2) & 1)*4;
    ushort4 o = *reinterpret_cast<const ushort4*>(&tile[d][s4*4]);
    *reinterpret_cast<ushort4*>(vtb + (size_t)(g*64 + d)*SEQ + st*64 + pos4) = o;
  }
}

// ---------------- causal flash GQA attention, 128-row tiles, split-KV ------
// Block = (head, 128-row q-tile, KV-half). 4 waves x 32 q-rows (2 streams).
// Per 64-key tile: K/V frags loaded once, 2x MFMA + 2x softmax (ILP).
// Parts both length qt+1: part0=[0,qt+1), part1=[qt+1,2qt+2).
// Grid 1024 = 4/CU; round-robin CU (h,j) gets lengths (16-j, j+1)x2 = 34.
// __launch_bounds__(256,4) pins VGPR<=128 so all 16 waves/CU are resident.
__global__ __launch_bounds__(256, 4) void k_attn(const ushort* __restrict__ qbuf,
                                                 const ushort* __restrict__ kbuf,
                                                 const ushort* __restrict__ vtb,
                                                 ushort* __restrict__ op,
                                                 float2* __restrict__ ml){
  __shared__ ushort Kd[2][64*64];       // swizzled K tiles   (16 KB)
  __shared__ ushort Vd[2][64*64];       // swizzled V^T tiles (16 KB)

  const int bx = blockIdx.x;
  const int c = bx & 255, slot = bx >> 8;
  const int h = c >> 3, j = c & 7;
  const int qt   = (slot & 1) ? j : 15 - j;
  const int part = slot >> 1;
  const int g = h >> 2;
  const int t0 = part ? (qt + 1)   : 0;
  const int t1 = part ? (2*qt + 2) : (qt + 1);
  const int tid = threadIdx.x, lane = tid & 63, wid = tid >> 6;
  const int l15 = lane & 15, u = lane >> 4;
  const int q0 = qt*128 + wid*32;       // wave's first q-row (2 streams of 16)

  // Q fragments for both streams (B-operand: col=l15 -> q-row)
  bf16x8 qf[2][2];
#pragma unroll
  for (int hh = 0; hh < 2; hh++)
#pragma unroll
    for (int kc = 0; kc < 2; kc++)
      qf[hh][kc] = *reinterpret_cast<const bf16x8*>(
          qbuf + (size_t)(q0 + hh*16 + l15)*2048 + h*64 + kc*32 + u*8);

  f32x4 o[2][4] = {};                   // per stream: O^T
  float mrun[2] = {-1e30f, -1e30f};
  float lrun[2] = {0.f, 0.f};

  // hoisted swizzled LDS byte-offsets (loop-invariant, static-indexed)
  int koff[8], voff[8];
#pragma unroll
  for (int kb = 0; kb < 4; kb++)
#pragma unroll
    for (int kc = 0; kc < 2; kc++){
      int keyl = kb*16 + l15;
      koff[kb*2+kc] = (keyl*64 + (((kc*4+u) ^ (keyl&7))*8)) * 2;
    }
#pragma unroll
  for (int kc = 0; kc < 2; kc++)
#pragma unroll
    for (int d0 = 0; d0 < 4; d0++){
      int vrow = d0*16 + l15;
      voff[kc*4+d0] = (vrow*64 + (((kc*4+u) ^ (vrow&7))*8)) * 2;
    }

  // staging: 8 chunks of 1KB per tile; wave does 2 K + 2 V
  const int srow = wid*16 + (lane >> 3);
  const int scol = ((lane & 7) ^ (lane >> 3)) * 8;
  const ushort* ksrc0 = kbuf + (size_t)srow*512 + g*64 + scol;
  const ushort* vsrc0 = vtb  + (size_t)(g*64 + srow)*SEQ + scol;

  auto STAGE = [&](int buf, int t){
    const ushort* ks = ksrc0 + (size_t)t*64*512;
    gl_lds16(ks,         &Kd[buf][wid*1024]);
    gl_lds16(ks + 8*512, &Kd[buf][wid*1024 + 512]);
    const ushort* vs = vsrc0 + t*64;
    gl_lds16(vs,          &Vd[buf][wid*1024]);
    gl_lds16(vs + 8*SEQ,  &Vd[buf][wid*1024 + 512]);
  };

  STAGE(0, t0);
  __syncthreads();   // drains vmcnt(0): first tile visible

  for (int t = t0; t < t1; t++){
    const int cur = (t - t0) & 1;
    if (t + 1 < t1) STAGE(cur ^ 1, t + 1);

    const char* KB = (const char*)Kd + cur*8192;
    const char* VB = (const char*)Vd + cur*8192;

    // ---- S^T = mfma(K, Q), both streams share K fragments ----
    f32x4 st[2][4];
#pragma unroll
    for (int kb = 0; kb < 4; kb++){
      const int key0 = t*64 + kb*16;
      bf16x8 kf0 = *reinterpret_cast<const bf16x8*>(KB + koff[kb*2]);
      bf16x8 kf1 = *reinterpret_cast<const bf16x8*>(KB + koff[kb*2+1]);
#pragma unroll
      for (int hh = 0; hh < 2; hh++){
        if (key0 <= q0 + hh*16 + 15){
          f32x4 a = {};
          a = __builtin_amdgcn_mfma_f32_16x16x32_bf16(kf0, qf[hh][0], a, 0, 0, 0);
          a = __builtin_amdgcn_mfma_f32_16x16x32_bf16(kf1, qf[hh][1], a, 0, 0, 0);
          st[hh][kb] = a;
        } else {
          st[hh][kb] = (f32x4){-1e30f, -1e30f, -1e30f, -1e30f};
        }
      }
    }
#pragma unroll
    for (int hh = 0; hh < 2; hh++){
      if (!((t*64 + 63) <= q0 + hh*16)){     // stream needs masking
        const int keyb = t*64 + u*4;
        const int qr = q0 + hh*16 + l15;
#pragma unroll
        for (int kb = 0; kb < 4; kb++)
#pragma unroll
          for (int jj = 0; jj < 4; jj++)
            st[hh][kb][jj] = (keyb + kb*16 + jj > qr) ? -1e30f : st[hh][kb][jj];
      }
    }

    // ---- online softmax (defer-max; raw v_exp + max3 tree), 2 streams ----
#pragma unroll
    for (int hh = 0; hh < 2; hh++){
      float r0 = fmax3(st[hh][0][0], st[hh][0][1], st[hh][0][2]);
      float r1 = fmax3(st[hh][0][3], st[hh][1][0], st[hh][1][1]);
      float r2 = fmax3(st[hh][1][2], st[hh][1][3], st[hh][2][0]);
      float r3 = fmax3(st[hh][2][1], st[hh][2][2], st[hh][2][3]);
      float r4 = fmax3(st[hh][3][0], st[hh][3][1], st[hh][3][2]);
      float m0 = fmax3(r0, r1, r2);
      float m1 = fmax3(r3, r4, st[hh][3][3]);
      float tml = fmaxf(m0, m1);
      if (__any(tml > mrun[hh] + THR2)){
        float tm = fmaxf(tml, __shfl_xor(tml, 16));
        tm = fmaxf(tm, __shfl_xor(tm, 32));
        float mn = fmaxf(mrun[hh], tm);
        float al = ex2(mrun[hh] - mn);
        mrun[hh] = mn;
        lrun[hh] *= al;
#pragma unroll
        for (int d0 = 0; d0 < 4; d0++)
#pragma unroll
          for (int jj = 0; jj < 4; jj++) o[hh][d0][jj] *= al;
      }
      float ls[4];
#pragma unroll
      for (int kb = 0; kb < 4; kb++){
        float p0 = ex2(st[hh][kb][0] - mrun[hh]);
        float p1 = ex2(st[hh][kb][1] - mrun[hh]);
        float p2 = ex2(st[hh][kb][2] - mrun[hh]);
        float p3 = ex2(st[hh][kb][3] - mrun[hh]);
        st[hh][kb][0] = p0; st[hh][kb][1] = p1;
        st[hh][kb][2] = p2; st[hh][kb][3] = p3;
        ls[kb] = (p0 + p1) + (p2 + p3);
      }
      lrun[hh] += (ls[0] + ls[1]) + (ls[2] + ls[3]);
    }

    // ---- O^T += V^T-frag x P-frag; V frags shared across streams ----
    __builtin_amdgcn_s_setprio(1);
#pragma unroll
    for (int kc = 0; kc < 2; kc++){
      union { uint32_t w[4]; bf16x8 v; } pb[2];
#pragma unroll
      for (int hh = 0; hh < 2; hh++){
        asm("v_cvt_pk_bf16_f32 %0, %1, %2" : "=v"(pb[hh].w[0]) : "v"(st[hh][2*kc  ][0]), "v"(st[hh][2*kc  ][1]));
        asm("v_cvt_pk_bf16_f32 %0, %1, %2" : "=v"(pb[hh].w[1]) : "v"(st[hh][2*kc  ][2]), "v"(st[hh][2*kc  ][3]));
        asm("v_cvt_pk_bf16_f32 %0, %1, %2" : "=v"(pb[hh].w[2]) : "v"(st[hh][2*kc+1][0]), "v"(st[hh][2*kc+1][1]));
        asm("v_cvt_pk_bf16_f32 %0, %1, %2" : "=v"(pb[hh].w[3]) : "v"(st[hh][2*kc+1][2]), "v"(st[hh][2*kc+1][3]));
      }
#pragma unroll
      for (int d0 = 0; d0 < 4; d0++){
        bf16x8 vb8 = *reinterpret_cast<const bf16x8*>(VB + voff[kc*4+d0]);
        o[0][d0] = __builtin_amdgcn_mfma_f32_16x16x32_bf16(vb8, pb[0].v, o[0][d0], 0, 0, 0);
        o[1][d0] = __builtin_amdgcn_mfma_f32_16x16x32_bf16(vb8, pb[1].v, o[1][d0], 0, 0, 0);
      }
    }
    __builtin_amdgcn_s_setprio(0);

    __syncthreads();  // publishes tile t+1 + protects buffer reuse
  }

  // epilogue: per stream, reduce lrun; store NORMALIZED partial O + (m,l)
#pragma unroll
  for (int hh = 0; hh < 2; hh++){
    float lt = lrun[hh] + __shfl_xor(lrun[hh], 16);
    lt += __shfl_xor(lt, 32);
    float inv = lt > 0.f ? 1.0f / lt : 0.f;
    const size_t ridx = (size_t)part*65536 + h*2048 + (q0 + hh*16 + l15);
#pragma unroll
    for (int d0 = 0; d0 < 4; d0++){
      ushort4 w;
      w.x = bf(o[hh][d0][0] * inv); w.y = bf(o[hh][d0][1] * inv);
      w.z = bf(o[hh][d0][2] * inv); w.w = bf(o[hh][d0][3] * inv);
      *reinterpret_cast<ushort4*>(&op[ridx*64 + d0*16 + u*4]) = w;
    }
    if (lane < 16) ml[ridx] = make_float2(mrun[hh], lt);
  }
}

// ---------------- combine two KV-half partials -> ctx bf16 ----------------
__global__ __launch_bounds__(256) void k_comb(const ushort* __restrict__ op,
                                              const float2* __restrict__ ml,
                                              ushort* __restrict__ ctx){
  const int tq = blockIdx.x*256 + threadIdx.x;
  const int q = tq & 3, row = (tq >> 2) & 2047, h = tq >> 13;
  const int idx = h*2048 + row;
  float2 a = ml[idx], b = ml[idx + 65536];
  float m = fmaxf(a.x, b.x);
  float w0 = ex2(a.x - m) * a.y;
  float w1 = ex2(b.x - m) * b.y;
  float inv = 1.0f / (w0 + w1);
  w0 *= inv; w1 *= inv;
  const ushort4* p0 = reinterpret_cast<const ushort4*>(op + (size_t)idx*64 + q*16);
  const ushort4* p1 = reinterpret_cast<const ushort4*>(op + ((size_t)idx + 65536)*64 + q*16);
  ushort* dst = ctx + (size_t)row*2048 + h*64 + q*16;
#pragma unroll
  for (int i = 0; i < 4; i++){
    ushort4 x0 = p0[i], x1 = p1[i];
    ushort4 w;
    w.x = bf(w0*b2f(x0.x) + w1*b2f(x1.x));
    w.y = bf(w0*b2f(x0.y) + w1*b2f(x1.y));
    w.z = bf(w0*b2f(x0.z) + w1*b2f(x1.z));
    w.w = bf(w0*b2f(x0.w) + w1*b2f(x1.w));
    reinterpret_cast<ushort4*>(dst)[i] = w;
  }
}

// ---------------- launcher ----------------
extern "C" void kernel_launch(void* const* d_in, const int* in_sizes, int n_in,
                              void* d_out, int out_size, void* d_ws, size_t ws_size,
                              hipStream_t stream){
  const float* x    = (const float*)d_in[0];
  // d_in[1] = mask (unused; causal mask computed analytically)
  const float* cosp = (const float*)d_in[2];
  const float* sinp = (const float*)d_in[3];
  const float* wq   = (const float*)d_in[4];
  const float* wk   = (const float*)d_in[5];
  const float* wv   = (const float*)d_in[6];
  const float* wo   = (const float*)d_in[7];
  const float* qg   = (const float*)d_in[8];
  const float* kg   = (const float*)d_in[9];
  float* out = (float*)d_out;

  char* ws = (char*)d_ws;
  ushort* xb   = (ushort*)(ws);                    //  8 MB  x bf16
  ushort* wcat = (ushort*)(ws + 8388608);          // 12 MB  [wq;wk;wv] bf16
  ushort* wob  = (ushort*)(ws + 20971520);         //  8 MB  wo bf16
  ushort* qkvc = (ushort*)(ws + 29360128);         // 12 MB  qkv bf16 [2048][3072]
  ushort* qb   = (ushort*)(ws + 41943040);         //  8 MB  q bf16 (pre-scaled)
  ushort* kb   = (ushort*)(ws + 50331648);         //  2 MB  k bf16 [2048][512]
  ushort* vtb  = (ushort*)(ws + 52428800);         //  2 MB  v^T bf16 (slot-ordered)
  ushort* ctxb = (ushort*)(ws + 54525952);         //  8 MB  ctx bf16
  // partials OVERLAY xb+wcat (dead after k_gemm_btc):
  ushort* op   = (ushort*)(ws);                    // 16 MB  [2][32][2048][64] bf16
  float2* ml   = (float2*)(ws + 16777216);         //  1 MB  [2][32][2048] float2
  // total 62,914,560 bytes

  k_cvt_all<<<14336, 256, 0, stream>>>(x, wq, wk, wv, wo, xb, wcat, wob);
  k_gemm_btc<<<dim3(32, 16), 256, 0, stream>>>(xb, wcat, qkvc, 2048, 3072, 2048);
  k_normrope<<<2048, 256, 0, stream>>>(qkvc, cosp, sinp, qg, kg, qb, kb);
  k_vtrans<<<256, 256, 0, stream>>>(qkvc, vtb);
  k_attn<<<1024, 256, 0, stream>>>(qb, kb, vtb, op, ml);
  k_comb<<<1024, 256, 0, stream>>>(op, ml, ctxb);
  k_gemm_bt<<<dim3(32, 16), 256, 0, stream>>>(ctxb, wob, out, 2048, 2048, 2048);
}

// Round 16
// 128.040 us; speedup vs baseline: 1.2039x; 1.0198x over previous
//
#include <hip/hip_runtime.h>
#include <stdint.h>

// Problem constants (fixed-shape problem)
#define SEQ    2048
#define DMODEL 2048
#define NHEAD  32
#define NKV    8
#define HDIM   64
#define NQKV   3072   // 2048 q + 512 k + 512 v

typedef __bf16 bf16x8 __attribute__((ext_vector_type(8)));
typedef float  f32x4  __attribute__((ext_vector_type(4)));
typedef unsigned short ushort8 __attribute__((ext_vector_type(8)));

#define SCALE2 0.180336880f   // 0.125 * log2(e): scores land in log2 domain
#define THR2   12.0f          // defer-max threshold (log2 domain); P <= 2^12

__device__ __forceinline__ ushort bf(float f){
  __bf16 h = (__bf16)f;               // native RNE convert on gfx950
  return __builtin_bit_cast(unsigned short, h);
}
__device__ __forceinline__ float b2f(ushort v){
  union { uint32_t u; float f; } a; a.u = ((uint32_t)v) << 16; return a.f;
}
__device__ __forceinline__ float ex2(float x){          // raw v_exp_f32
  return __builtin_amdgcn_exp2f(x);
}
__device__ __forceinline__ float fmax3(float a, float b, float c){
  float r;
  asm("v_max3_f32 %0, %1, %2, %3" : "=v"(r) : "v"(a), "v"(b), "v"(c));
  return r;
}

__device__ __forceinline__ void gl_lds16(const void* g, void* l){
  __builtin_amdgcn_global_load_lds(
      (const __attribute__((address_space(1))) uint32_t*)g,
      (__attribute__((address_space(3))) uint32_t*)l, 16, 0, 0);
}

// ------------- all f32->bf16 converts in one kernel -------------
__global__ __launch_bounds__(256) void k_cvt_all(const float* __restrict__ x,
                                                 const float* __restrict__ wq,
                                                 const float* __restrict__ wk,
                                                 const float* __restrict__ wv,
                                                 const float* __restrict__ wo,
                                                 ushort* __restrict__ xb,
                                                 ushort* __restrict__ wcat,
                                                 ushort* __restrict__ wob){
  int i = blockIdx.x * 256 + threadIdx.x;
  const float* src; ushort* dst; int s4; int d4;
  if (i < 1048576)      { src = x;  dst = xb;   s4 = i;           d4 = s4; }
  else if (i < 2097152) { src = wq; dst = wcat; s4 = i - 1048576; d4 = s4; }
  else if (i < 2359296) { src = wk; dst = wcat; s4 = i - 2097152; d4 = s4 + 1048576; }
  else if (i < 2621440) { src = wv; dst = wcat; s4 = i - 2359296; d4 = s4 + 1310720; }
  else                  { src = wo; dst = wob;  s4 = i - 2621440; d4 = s4; }
  float4 v = reinterpret_cast<const float4*>(src)[s4];
  ushort4 o;
  o.x = bf(v.x); o.y = bf(v.y); o.z = bf(v.z); o.w = bf(v.w);
  reinterpret_cast<ushort4*>(dst)[d4] = o;
}

// ---------------- GEMM (f32 out): C = A[M][K] x B[N][K]^T ----------------
// Tile 128x64, BK=64, 4 waves (2x2; per-wave 64x32). Grid (N/64, M/128) =
// 512 blocks = exactly 2/CU, LDS 49KB -> both resident, 8 waves/CU.
__global__ __launch_bounds__(256) void k_gemm_bt(const ushort* __restrict__ A,
                                                 const ushort* __restrict__ B,
                                                 float* __restrict__ C,
                                                 int M, int N, int K){
  __shared__ ushort As[2][128*64];
  __shared__ ushort Bs[2][64*64];
  const int tid = threadIdx.x, lane = tid & 63, wid = tid >> 6;
  const int bm = blockIdx.y * 128, bn = blockIdx.x * 64;
  const int wr = wid >> 1, wc = wid & 1;
  const int l15 = lane & 15, u = lane >> 4;

  const int crow = lane >> 3;                       // row within 8-row chunk
  const int scol = ((lane & 7) ^ crow) * 8;         // pre-swizzled 16B slot
  const ushort* Abase = A + (size_t)(bm + wid*32 + crow) * K + scol;
  const ushort* Bbase = B + (size_t)(bn + wid*16 + crow) * K + scol;

  auto STAGE = [&](int buf, int k0){
#pragma unroll
    for (int c = 0; c < 4; c++)
      gl_lds16(Abase + k0 + (size_t)c*8*K, &As[buf][(wid*32 + c*8)*64]);
#pragma unroll
    for (int c = 0; c < 2; c++)
      gl_lds16(Bbase + k0 + (size_t)c*8*K, &Bs[buf][(wid*16 + c*8)*64]);
  };

  f32x4 acc[4][2] = {};
  const int NT = K >> 6;

  STAGE(0, 0);
  __syncthreads();

  for (int t = 0; t < NT; t++){
    const int cur = t & 1;
    if (t + 1 < NT) STAGE(cur ^ 1, (t + 1) << 6);

#pragma unroll
    for (int kc = 0; kc < 2; kc++){
      bf16x8 af[4], bfr[2];
#pragma unroll
      for (int m = 0; m < 4; m++){
        int row = wr*64 + m*16 + l15;
        af[m] = *reinterpret_cast<const bf16x8*>(&As[cur][row*64 + (((kc*4+u) ^ (row&7))*8)]);
      }
#pragma unroll
      for (int n = 0; n < 2; n++){
        int row = wc*32 + n*16 + l15;
        bfr[n] = *reinterpret_cast<const bf16x8*>(&Bs[cur][row*64 + (((kc*4+u) ^ (row&7))*8)]);
      }
      __builtin_amdgcn_s_setprio(1);
#pragma unroll
      for (int m = 0; m < 4; m++)
#pragma unroll
        for (int n = 0; n < 2; n++)
          acc[m][n] = __builtin_amdgcn_mfma_f32_16x16x32_bf16(af[m], bfr[n], acc[m][n], 0, 0, 0);
      __builtin_amdgcn_s_setprio(0);
    }

    __syncthreads();
  }

#pragma unroll
  for (int m = 0; m < 4; m++)
#pragma unroll
    for (int n = 0; n < 2; n++)
#pragma unroll
      for (int j = 0; j < 4; j++){
        int row = bm + wr*64 + m*16 + u*4 + j;
        int col = bn + wc*32 + n*16 + l15;
        C[(size_t)row * N + col] = acc[m][n][j];
      }
}

// ---------------- GEMM (bf16 out): qkvc = xb x wcat^T ----------------
// Tile 128x96, BK=64, 4 waves (2x2; per-wave 64x48). Grid (32,16) = 512
// blocks = exactly 2/CU, LDS 57KB -> both resident.
__global__ __launch_bounds__(256) void k_gemm_btc(const ushort* __restrict__ A,
                                                  const ushort* __restrict__ B,
                                                  ushort* __restrict__ C,
                                                  int M, int N, int K){
  __shared__ ushort As[2][128*64];
  __shared__ ushort Bs[2][96*64];
  const int tid = threadIdx.x, lane = tid & 63, wid = tid >> 6;
  const int bm = blockIdx.y * 128, bn = blockIdx.x * 96;
  const int wr = wid >> 1, wc = wid & 1;
  const int l15 = lane & 15, u = lane >> 4;

  const int crow = lane >> 3;
  const int scol = ((lane & 7) ^ crow) * 8;
  const ushort* Abase = A + (size_t)(bm + wid*32 + crow) * K + scol;
  const ushort* Bbase = B + (size_t)(bn + wid*24 + crow) * K + scol;

  auto STAGE = [&](int buf, int k0){
#pragma unroll
    for (int c = 0; c < 4; c++)
      gl_lds16(Abase + k0 + (size_t)c*8*K, &As[buf][(wid*32 + c*8)*64]);
#pragma unroll
    for (int c = 0; c < 3; c++)
      gl_lds16(Bbase + k0 + (size_t)c*8*K, &Bs[buf][(wid*24 + c*8)*64]);
  };

  f32x4 acc[4][3] = {};
  const int NT = K >> 6;

  STAGE(0, 0);
  __syncthreads();

  for (int t = 0; t < NT; t++){
    const int cur = t & 1;
    if (t + 1 < NT) STAGE(cur ^ 1, (t + 1) << 6);

#pragma unroll
    for (int kc = 0; kc < 2; kc++){
      bf16x8 af[4], bfr[3];
#pragma unroll
      for (int m = 0; m < 4; m++){
        int row = wr*64 + m*16 + l15;
        af[m] = *reinterpret_cast<const bf16x8*>(&As[cur][row*64 + (((kc*4+u) ^ (row&7))*8)]);
      }
#pragma unroll
      for (int n = 0; n < 3; n++){
        int row = wc*48 + n*16 + l15;
        bfr[n] = *reinterpret_cast<const bf16x8*>(&Bs[cur][row*64 + (((kc*4+u) ^ (row&7))*8)]);
      }
      __builtin_amdgcn_s_setprio(1);
#pragma unroll
      for (int m = 0; m < 4; m++)
#pragma unroll
        for (int n = 0; n < 3; n++)
          acc[m][n] = __builtin_amdgcn_mfma_f32_16x16x32_bf16(af[m], bfr[n], acc[m][n], 0, 0, 0);
      __builtin_amdgcn_s_setprio(0);
    }

    __syncthreads();
  }

#pragma unroll
  for (int m = 0; m < 4; m++)
#pragma unroll
    for (int n = 0; n < 3; n++)
#pragma unroll
      for (int j = 0; j < 4; j++){
        int row = bm + wr*64 + m*16 + u*4 + j;
        int col = bn + wc*48 + n*16 + l15;
        C[(size_t)row * N + col] = bf(acc[m][n][j]);
      }
}

// ------- fused prep: RMSNorm+RoPE (q,k) AND V transpose, one kernel -------
// blocks [0,2048): normrope for s-row bx; blocks [2048,2304): vtrans tile.
__global__ __launch_bounds__(256) void k_prep(const ushort* __restrict__ qkvc,
                                              const float* __restrict__ cosp,
                                              const float* __restrict__ sinp,
                                              const float* __restrict__ qg,
                                              const float* __restrict__ kg,
                                              ushort* __restrict__ qb,
                                              ushort* __restrict__ kb,
                                              ushort* __restrict__ vtb){
  __shared__ ushort tile[64][68];     // vtrans path only
  const int bx = blockIdx.x;
  const int tid = threadIdx.x, lane = tid & 63, wid = tid >> 6;

  if (bx < 2048){
    // ---- RMSNorm + RoPE (q pre-scaled by SCALE2, k plain) ----
    const int s = bx;
    const ushort* row = qkvc + (size_t)s * NQKV;
    const float cs = cosp[s*HDIM + lane];
    const float sn = sinp[s*HDIM + lane];
    for (int hidx = wid; hidx < 40; hidx += 4){
      const bool isq = hidx < 32;
      const int col = isq ? hidx*64 : 2048 + (hidx-32)*64;
      float x = b2f(row[col + lane]);
      float ss = x * x;
#pragma unroll
      for (int m = 1; m < 64; m <<= 1) ss += __shfl_xor(ss, m);
      float r = rsqrtf(ss * (1.0f/64.0f) + 1e-6f);
      float y = x * r * (isq ? qg : kg)[lane];
      float p = __shfl_xor(y, 32);
      float out = y * cs + (lane < 32 ? -p : p) * sn;
      if (isq) qb[(size_t)s*2048 + hidx*64 + lane] = bf(out * SCALE2);
      else     kb[(size_t)s*512 + (hidx-32)*64 + lane] = bf(out);
    }
  } else {
    // ---- V transpose into vtb (slot-ordered for PV in-lane P) ----
    const int b = bx - 2048;
    const int g = b >> 5, st = b & 31;
#pragma unroll
    for (int i = 0; i < 4; i++){
      int idx = i*256 + tid;
      int r = idx >> 4, c4 = idx & 15;
      ushort4 v = *reinterpret_cast<const ushort4*>(
          qkvc + (size_t)(st*64 + r)*NQKV + 2560 + g*64 + c4*4);
      tile[c4*4+0][r] = v.x;
      tile[c4*4+1][r] = v.y;
      tile[c4*4+2][r] = v.z;
      tile[c4*4+3][r] = v.w;
    }
    __syncthreads();
#pragma unroll
    for (int i = 0; i < 4; i++){
      int idx = i*256 + tid;
      int d = idx >> 4, s4 = idx & 15;
      // sigma: key chunk s4=(kb,u) -> PV-slot-ordered position
      int pos4 = (s4 >> 3)*32 + (s4 & 3)*8 + ((s4 >> 2) & 1)*4;
      ushort4 o = *reinterpret_cast<const ushort4*>(&tile[d][s4*4]);
      *reinterpret_cast<ushort4*>(vtb + (size_t)(g*64 + d)*SEQ + st*64 + pos4) = o;
    }
  }
}

// ---------------- causal flash GQA attention, 128-row tiles, split-KV ------
// Block = (head, 128-row q-tile, KV-half). 4 waves x 32 q-rows (2 streams).
// Per 64-key tile: K/V frags loaded once, 2x MFMA + 2x softmax (ILP).
// Parts both length qt+1: part0=[0,qt+1), part1=[qt+1,2qt+2).
// Grid 1024 = 4/CU; round-robin CU (h,j) gets lengths (16-j, j+1)x2 = 34.
// __launch_bounds__(256,4) pins VGPR<=128 -> 16 waves/CU resident (the cap).
__global__ __launch_bounds__(256, 4) void k_attn(const ushort* __restrict__ qbuf,
                                                 const ushort* __restrict__ kbuf,
                                                 const ushort* __restrict__ vtb,
                                                 ushort* __restrict__ op,
                                                 float2* __restrict__ ml){
  __shared__ ushort Kd[2][64*64];       // swizzled K tiles   (16 KB)
  __shared__ ushort Vd[2][64*64];       // swizzled V^T tiles (16 KB)

  const int bx = blockIdx.x;
  const int c = bx & 255, slot = bx >> 8;
  const int h = c >> 3, j = c & 7;
  const int qt   = (slot & 1) ? j : 15 - j;
  const int part = slot >> 1;
  const int g = h >> 2;
  const int t0 = part ? (qt + 1)   : 0;
  const int t1 = part ? (2*qt + 2) : (qt + 1);
  const int tid = threadIdx.x, lane = tid & 63, wid = tid >> 6;
  const int l15 = lane & 15, u = lane >> 4;
  const int q0 = qt*128 + wid*32;       // wave's first q-row (2 streams of 16)

  // Q fragments for both streams (B-operand: col=l15 -> q-row)
  bf16x8 qf[2][2];
#pragma unroll
  for (int hh = 0; hh < 2; hh++)
#pragma unroll
    for (int kc = 0; kc < 2; kc++)
      qf[hh][kc] = *reinterpret_cast<const bf16x8*>(
          qbuf + (size_t)(q0 + hh*16 + l15)*2048 + h*64 + kc*32 + u*8);

  f32x4 o[2][4] = {};                   // per stream: O^T
  float mrun[2] = {-1e30f, -1e30f};
  float lrun[2] = {0.f, 0.f};

  // hoisted swizzled LDS byte-offsets (loop-invariant, static-indexed)
  int koff[8], voff[8];
#pragma unroll
  for (int kb = 0; kb < 4; kb++)
#pragma unroll
    for (int kc = 0; kc < 2; kc++){
      int keyl = kb*16 + l15;
      koff[kb*2+kc] = (keyl*64 + (((kc*4+u) ^ (keyl&7))*8)) * 2;
    }
#pragma unroll
  for (int kc = 0; kc < 2; kc++)
#pragma unroll
    for (int d0 = 0; d0 < 4; d0++){
      int vrow = d0*16 + l15;
      voff[kc*4+d0] = (vrow*64 + (((kc*4+u) ^ (vrow&7))*8)) * 2;
    }

  // staging: 8 chunks of 1KB per tile; wave does 2 K + 2 V
  const int srow = wid*16 + (lane >> 3);
  const int scol = ((lane & 7) ^ (lane >> 3)) * 8;
  const ushort* ksrc0 = kbuf + (size_t)srow*512 + g*64 + scol;
  const ushort* vsrc0 = vtb  + (size_t)(g*64 + srow)*SEQ + scol;

  auto STAGE = [&](int buf, int t){
    const ushort* ks = ksrc0 + (size_t)t*64*512;
    gl_lds16(ks,         &Kd[buf][wid*1024]);
    gl_lds16(ks + 8*512, &Kd[buf][wid*1024 + 512]);
    const ushort* vs = vsrc0 + t*64;
    gl_lds16(vs,          &Vd[buf][wid*1024]);
    gl_lds16(vs + 8*SEQ,  &Vd[buf][wid*1024 + 512]);
  };

  STAGE(0, t0);
  __syncthreads();   // drains vmcnt(0): first tile visible

  for (int t = t0; t < t1; t++){
    const int cur = (t - t0) & 1;
    if (t + 1 < t1) STAGE(cur ^ 1, t + 1);

    const char* KB = (const char*)Kd + cur*8192;
    const char* VB = (const char*)Vd + cur*8192;

    // ---- S^T = mfma(K, Q), both streams share K fragments ----
    f32x4 st[2][4];
    __builtin_amdgcn_s_setprio(1);
#pragma unroll
    for (int kb = 0; kb < 4; kb++){
      const int key0 = t*64 + kb*16;
      bf16x8 kf0 = *reinterpret_cast<const bf16x8*>(KB + koff[kb*2]);
      bf16x8 kf1 = *reinterpret_cast<const bf16x8*>(KB + koff[kb*2+1]);
#pragma unroll
      for (int hh = 0; hh < 2; hh++){
        if (key0 <= q0 + hh*16 + 15){
          f32x4 a = {};
          a = __builtin_amdgcn_mfma_f32_16x16x32_bf16(kf0, qf[hh][0], a, 0, 0, 0);
          a = __builtin_amdgcn_mfma_f32_16x16x32_bf16(kf1, qf[hh][1], a, 0, 0, 0);
          st[hh][kb] = a;
        } else {
          st[hh][kb] = (f32x4){-1e30f, -1e30f, -1e30f, -1e30f};
        }
      }
    }
    __builtin_amdgcn_s_setprio(0);
#pragma unroll
    for (int hh = 0; hh < 2; hh++){
      if (!((t*64 + 63) <= q0 + hh*16)){     // stream needs masking
        const int keyb = t*64 + u*4;
        const int qr = q0 + hh*16 + l15;
#pragma unroll
        for (int kb = 0; kb < 4; kb++)
#pragma unroll
          for (int jj = 0; jj < 4; jj++)
            st[hh][kb][jj] = (keyb + kb*16 + jj > qr) ? -1e30f : st[hh][kb][jj];
      }
    }

    // ---- online softmax (defer-max; raw v_exp + max3 tree), 2 streams ----
#pragma unroll
    for (int hh = 0; hh < 2; hh++){
      float r0 = fmax3(st[hh][0][0], st[hh][0][1], st[hh][0][2]);
      float r1 = fmax3(st[hh][0][3], st[hh][1][0], st[hh][1][1]);
      float r2 = fmax3(st[hh][1][2], st[hh][1][3], st[hh][2][0]);
      float r3 = fmax3(st[hh][2][1], st[hh][2][2], st[hh][2][3]);
      float r4 = fmax3(st[hh][3][0], st[hh][3][1], st[hh][3][2]);
      float m0 = fmax3(r0, r1, r2);
      float m1 = fmax3(r3, r4, st[hh][3][3]);
      float tml = fmaxf(m0, m1);
      if (__any(tml > mrun[hh] + THR2)){
        float tm = fmaxf(tml, __shfl_xor(tml, 16));
        tm = fmaxf(tm, __shfl_xor(tm, 32));
        float mn = fmaxf(mrun[hh], tm);
        float al = ex2(mrun[hh] - mn);
        mrun[hh] = mn;
        lrun[hh] *= al;
#pragma unroll
        for (int d0 = 0; d0 < 4; d0++)
#pragma unroll
          for (int jj = 0; jj < 4; jj++) o[hh][d0][jj] *= al;
      }
      float ls[4];
#pragma unroll
      for (int kb = 0; kb < 4; kb++){
        float p0 = ex2(st[hh][kb][0] - mrun[hh]);
        float p1 = ex2(st[hh][kb][1] - mrun[hh]);
        float p2 = ex2(st[hh][kb][2] - mrun[hh]);
        float p3 = ex2(st[hh][kb][3] - mrun[hh]);
        st[hh][kb][0] = p0; st[hh][kb][1] = p1;
        st[hh][kb][2] = p2; st[hh][kb][3] = p3;
        ls[kb] = (p0 + p1) + (p2 + p3);
      }
      lrun[hh] += (ls[0] + ls[1]) + (ls[2] + ls[3]);
    }

    // ---- O^T += V^T-frag x P-frag; V frags shared across streams ----
    __builtin_amdgcn_s_setprio(1);
#pragma unroll
    for (int kc = 0; kc < 2; kc++){
      union { uint32_t w[4]; bf16x8 v; } pb[2];
#pragma unroll
      for (int hh = 0; hh < 2; hh++){
        asm("v_cvt_pk_bf16_f32 %0, %1, %2" : "=v"(pb[hh].w[0]) : "v"(st[hh][2*kc  ][0]), "v"(st[hh][2*kc  ][1]));
        asm("v_cvt_pk_bf16_f32 %0, %1, %2" : "=v"(pb[hh].w[1]) : "v"(st[hh][2*kc  ][2]), "v"(st[hh][2*kc  ][3]));
        asm("v_cvt_pk_bf16_f32 %0, %1, %2" : "=v"(pb[hh].w[2]) : "v"(st[hh][2*kc+1][0]), "v"(st[hh][2*kc+1][1]));
        asm("v_cvt_pk_bf16_f32 %0, %1, %2" : "=v"(pb[hh].w[3]) : "v"(st[hh][2*kc+1][2]), "v"(st[hh][2*kc+1][3]));
      }
#pragma unroll
      for (int d0 = 0; d0 < 4; d0++){
        bf16x8 vb8 = *reinterpret_cast<const bf16x8*>(VB + voff[kc*4+d0]);
        o[0][d0] = __builtin_amdgcn_mfma_f32_16x16x32_bf16(vb8, pb[0].v, o[0][d0], 0, 0, 0);
        o[1][d0] = __builtin_amdgcn_mfma_f32_16x16x32_bf16(vb8, pb[1].v, o[1][d0], 0, 0, 0);
      }
    }
    __builtin_amdgcn_s_setprio(0);

    __syncthreads();  // publishes tile t+1 + protects buffer reuse
  }

  // epilogue: per stream, reduce lrun; store NORMALIZED partial O + (m,l)
#pragma unroll
  for (int hh = 0; hh < 2; hh++){
    float lt = lrun[hh] + __shfl_xor(lrun[hh], 16);
    lt += __shfl_xor(lt, 32);
    float inv = lt > 0.f ? 1.0f / lt : 0.f;
    const size_t ridx = (size_t)part*65536 + h*2048 + (q0 + hh*16 + l15);
#pragma unroll
    for (int d0 = 0; d0 < 4; d0++){
      ushort4 w;
      w.x = bf(o[hh][d0][0] * inv); w.y = bf(o[hh][d0][1] * inv);
      w.z = bf(o[hh][d0][2] * inv); w.w = bf(o[hh][d0][3] * inv);
      *reinterpret_cast<ushort4*>(&op[ridx*64 + d0*16 + u*4]) = w;
    }
    if (lane < 16) ml[ridx] = make_float2(mrun[hh], lt);
  }
}

// ---------------- combine two KV-half partials -> ctx bf16 ----------------
__global__ __launch_bounds__(256) void k_comb(const ushort* __restrict__ op,
                                              const float2* __restrict__ ml,
                                              ushort* __restrict__ ctx){
  const int tq = blockIdx.x*256 + threadIdx.x;
  const int q = tq & 3, row = (tq >> 2) & 2047, h = tq >> 13;
  const int idx = h*2048 + row;
  float2 a = ml[idx], b = ml[idx + 65536];
  float m = fmaxf(a.x, b.x);
  float w0 = ex2(a.x - m) * a.y;
  float w1 = ex2(b.x - m) * b.y;
  float inv = 1.0f / (w0 + w1);
  w0 *= inv; w1 *= inv;
  const ushort8* p0 = reinterpret_cast<const ushort8*>(op + (size_t)idx*64 + q*16);
  const ushort8* p1 = reinterpret_cast<const ushort8*>(op + ((size_t)idx + 65536)*64 + q*16);
  ushort* dst = ctx + (size_t)row*2048 + h*64 + q*16;
#pragma unroll
  for (int i = 0; i < 2; i++){
    ushort8 x0 = p0[i], x1 = p1[i];
    ushort8 w;
#pragma unroll
    for (int e = 0; e < 8; e++)
      w[e] = bf(w0*b2f(x0[e]) + w1*b2f(x1[e]));
    reinterpret_cast<ushort8*>(dst)[i] = w;
  }
}

// ---------------- launcher ----------------
extern "C" void kernel_launch(void* const* d_in, const int* in_sizes, int n_in,
                              void* d_out, int out_size, void* d_ws, size_t ws_size,
                              hipStream_t stream){
  const float* x    = (const float*)d_in[0];
  // d_in[1] = mask (unused; causal mask computed analytically)
  const float* cosp = (const float*)d_in[2];
  const float* sinp = (const float*)d_in[3];
  const float* wq   = (const float*)d_in[4];
  const float* wk   = (const float*)d_in[5];
  const float* wv   = (const float*)d_in[6];
  const float* wo   = (const float*)d_in[7];
  const float* qg   = (const float*)d_in[8];
  const float* kg   = (const float*)d_in[9];
  float* out = (float*)d_out;

  char* ws = (char*)d_ws;
  ushort* xb   = (ushort*)(ws);                    //  8 MB  x bf16
  ushort* wcat = (ushort*)(ws + 8388608);          // 12 MB  [wq;wk;wv] bf16
  ushort* wob  = (ushort*)(ws + 20971520);         //  8 MB  wo bf16
  ushort* qkvc = (ushort*)(ws + 29360128);         // 12 MB  qkv bf16 [2048][3072]
  ushort* qb   = (ushort*)(ws + 41943040);         //  8 MB  q bf16 (pre-scaled)
  ushort* kb   = (ushort*)(ws + 50331648);         //  2 MB  k bf16 [2048][512]
  ushort* vtb  = (ushort*)(ws + 52428800);         //  2 MB  v^T bf16 (slot-ordered)
  ushort* ctxb = (ushort*)(ws + 54525952);         //  8 MB  ctx bf16
  // partials OVERLAY xb+wcat (dead after k_gemm_btc):
  ushort* op   = (ushort*)(ws);                    // 16 MB  [2][32][2048][64] bf16
  float2* ml   = (float2*)(ws + 16777216);         //  1 MB  [2][32][2048] float2
  // total 62,914,560 bytes

  k_cvt_all<<<14336, 256, 0, stream>>>(x, wq, wk, wv, wo, xb, wcat, wob);
  k_gemm_btc<<<dim3(32, 16), 256, 0, stream>>>(xb, wcat, qkvc, 2048, 3072, 2048);
  k_prep<<<2304, 256, 0, stream>>>(qkvc, cosp, sinp, qg, kg, qb, kb, vtb);
  k_attn<<<1024, 256, 0, stream>>>(qb, kb, vtb, op, ml);
  k_comb<<<1024, 256, 0, stream>>>(op, ml, ctxb);
  k_gemm_bt<<<dim3(32, 16), 256, 0, stream>>>(ctxb, wob, out, 2048, 2048, 2048);
}